// Round 8
// baseline (238.291 us; speedup 1.0000x reference)
//
#include <hip/hip_runtime.h>
#include <hip/hip_bf16.h>

// Inputs/outputs are FLOAT32 (reference dtype). bf16 used only internally for MFMA.
typedef __bf16 bf16_t;
typedef bf16_t bf16x8 __attribute__((ext_vector_type(8)));
typedef bf16_t bf16x4 __attribute__((ext_vector_type(4)));
typedef float  f32x4  __attribute__((ext_vector_type(4)));

#define MFMA(a,b,c) __builtin_amdgcn_mfma_f32_16x16x32_bf16((a),(b),(c),0,0,0)

// =================== LAUNCH A: k_front (1789 blocks) ===================
// roles by blockIdx.x:
//   [0,256)     : M = final_w[:, :256] @ gw_w  (bf16)
//   [256,316)   : qkv = emb @ {wq,wk,wv} + bias
//   [316,444)   : phis (8 roles x 16 b): fB, fBT, s_raw, csum, fmax/cmax, xsump
//   [444,464)   : E1 = emb @ gc1_w  [20][256]
//   [464,765)   : WG1 = wo @ gc1_w [300][256]; row 300 = bg1 = bo @ gc1_w
//   [765,1789)  : xT transpose: raw [1024q][256c] fp32 -> xT [256c][1024q] bf16
__global__ __launch_bounds__(256) void k_front(
    const float* final_w, const float* gw_w, const float* emb,
    const float* wq, const float* bq, const float* wk, const float* bk,
    const float* wv, const float* bvv, const float* x,
    const float* phi_w, const float* phi_b, const float* s2l_w,
    const float* gc1_w, const float* wo, const float* bo,
    bf16_t* M16, float* qkv, bf16_t* fB, bf16_t* fBT, float* s_raw,
    float* xsump, float* csum, float* fmaxp, float* cmaxp, bf16_t* xT,
    float* E1, float* WG1, float* bg1) {
  __shared__ __align__(16) char sp[27648];
  int bid = blockIdx.x, t = threadIdx.x;
  if (bid < 256) {                       // ---- k_M ----
    float* fw = (float*)sp;
    int o = bid, c = t;
    fw[c] = final_w[o*512 + c];
    __syncthreads();
    float acc = 0.f;
    for (int k = 0; k < 256; ++k) acc += fw[k] * gw_w[k*256 + c];
    M16[o*256 + c] = (bf16_t)acc;
    return;
  }
  if (bid < 316) {                       // ---- k_qkv ----
    int id = bid - 256;
    int mat = id / 20, row = id % 20;
    const float* W  = mat == 0 ? wq : (mat == 1 ? wk : wv);
    const float* Bb = mat == 0 ? bq : (mat == 1 ? bk : bvv);
    float* er = (float*)sp;
    for (int i = t; i < 300; i += 256) er[i] = emb[row*300 + i];
    __syncthreads();
    for (int o = t; o < 300; o += 256) {
      float acc = Bb[o];
      for (int d = 0; d < 300; ++d) acc += er[d] * W[d*300 + o];
      qkv[(mat*20 + row)*300 + o] = acc;
    }
    return;
  }
  if (bid < 444) {                       // ---- k_phis ----
    int id = bid - 316;
    int b = id >> 3, role = id & 7;
    const float* xb = x + b*262144;
    float* pw = (float*)sp;              // 4096
    float* wi = pw + 4096;               // 256
    float* pb = wi + 256;                // 16
    float* phs = pb + 16;                // [128][18]
    unsigned* fmu = (unsigned*)(phs + 2304);  // 16
    unsigned* cmu = fmu + 16;            // 1
    for (int i = t; i < 4096; i += 256) pw[i] = phi_w[i];
    wi[t] = s2l_w[t];
    if (t < 16) { pb[t] = phi_b[t]; fmu[t] = 0u; }
    if (t == 0) cmu[0] = 0u;
    __syncthreads();
    int hwl = t & 127, half = t >> 7;
    int hw = role*128 + hwl;
    float ph[16];
    #pragma unroll
    for (int o = 0; o < 16; ++o) ph[o] = 0.f;
    float sacc = 0.f;
    for (int ci = 0; ci < 128; ++ci) {
      int c = half*128 + ci;
      float xv = xb[c*1024 + hw];
      sacc += wi[c] * xv;
      #pragma unroll
      for (int o = 0; o < 16; ++o) ph[o] += pw[o*256 + c] * xv;
    }
    if (half == 0) {
      #pragma unroll
      for (int o = 0; o < 16; ++o) phs[hwl*18 + o] = ph[o];
      phs[hwl*18 + 16] = sacc;
    }
    __syncthreads();
    if (half == 1) {
      #pragma unroll
      for (int o = 0; o < 16; ++o) phs[hwl*18 + o] += ph[o];
      s_raw[b*1024 + hw] = phs[hwl*18 + 16] + sacc;
    }
    __syncthreads();
    float csacc = 0.f;
    #pragma unroll
    for (int i = 0; i < 8; ++i) {
      int j = i*256 + t;
      int o = j >> 7, hl = j & 127;
      float val = fmaxf(phs[hl*18 + o] + pb[o], 0.f);
      bf16_t bv16 = (bf16_t)val;
      atomicMax(&fmu[o], __float_as_uint((float)bv16));
      fB [b*16384 + o*1024 + role*128 + hl] = bv16;            // m-major (raw)
      fBT[b*16384 + (role*128 + hl)*16 + o] = bv16;            // q-major
      csacc += (float)bv16;
    }
    if (half == 0) phs[hwl*18 + 17] = csacc;
    __syncthreads();
    if (half == 1) {
      float cs = phs[hwl*18 + 17] + csacc;
      csum[b*1024 + hw] = cs;
      atomicMax(cmu, __float_as_uint(cs));
    }
    if (t < 16) fmaxp[b*128 + role*16 + t] = __uint_as_float(fmu[t]);
    __syncthreads();
    if (t == 0) cmaxp[b*8 + role] = __uint_as_float(cmu[0]);
    // xsum partial for this (b, role): L2-hot re-read, thread owns channel c = t
    {
      const f32x4* xr = (const f32x4*)(xb + t*1024 + role*128);
      float s4 = 0.f;
      #pragma unroll
      for (int j = 0; j < 32; ++j) { f32x4 v = xr[j]; s4 += v[0] + v[1] + v[2] + v[3]; }
      xsump[(b*8 + role)*256 + t] = s4;
    }
    return;
  }
  if (bid < 464) {                       // ---- E1 = emb @ gc1_w ----
    int n = bid - 444;
    float* er = (float*)sp;
    for (int i = t; i < 300; i += 256) er[i] = emb[n*300 + i];
    __syncthreads();
    float acc = 0.f;
    for (int d = 0; d < 300; ++d) acc += er[d] * gc1_w[d*256 + t];
    E1[n*256 + t] = acc;
    return;
  }
  if (bid < 765) {                       // ---- WG1 rows / bg1 ----
    int d0 = bid - 464;                  // 0..300
    float* er = (float*)sp;
    if (d0 < 300) { for (int i = t; i < 300; i += 256) er[i] = wo[d0*300 + i]; }
    else          { for (int i = t; i < 300; i += 256) er[i] = bo[i]; }
    __syncthreads();
    float acc = 0.f;
    for (int e = 0; e < 300; ++e) acc += er[e] * gc1_w[e*256 + t];
    if (d0 < 300) WG1[d0*256 + t] = acc; else bg1[t] = acc;
    return;
  }
  {                                      // ---- k_xt: raw-reshape transpose ----
    int id = bid - 765;                  // 0..1023
    int bb = id >> 6, tile = id & 63;
    int q0 = (tile >> 2) * 64, c0 = (tile & 3) * 64;
    bf16_t* tl = (bf16_t*)sp;            // [64][74]
    const float* xbb = x + bb*262144;
    #pragma unroll
    for (int k = 0; k < 16; ++k) {
      int idx = k*256 + t, qi = idx >> 6, ci = idx & 63;
      tl[ci*74 + qi] = (bf16_t)xbb[(q0 + qi)*256 + c0 + ci];
    }
    __syncthreads();
    #pragma unroll
    for (int k = 0; k < 16; ++k) {
      int idx = k*256 + t, ci = idx >> 6, qi = idx & 63;
      xT[bb*262144 + (c0 + ci)*1024 + q0 + qi] = tl[ci*74 + qi];
    }
    return;
  }
}

// =================== LAUNCH B: k_mid1 (18 blocks x 512) ===================
__global__ __launch_bounds__(512) void k_mid1(
    const float* adj, const float* qkv, const float* E1,
    const float* glob_w, const float* xsump, const float* s_raw,
    const float* fmaxp, const float* cmaxp,
    float* n1g, float* adjng, float* rsAg, float* AE1g,
    float* dgd, float* mcol, float* fmaxb, float* cmaxb) {
  __shared__ __align__(16) float sp[12480];
  int t = threadIdx.x;
  if (blockIdx.x == 0) {                 // ---- attention -> n1 ----
    float* A  = sp;            // 6000 q
    float* Bs = A + 6000;      // 6000 k
    float* att  = Bs + 6000;   // 400
    float* wsum = att + 400;   // 20
    for (int i = t; i < 6000; i += 512) { A[i] = qkv[i]; Bs[i] = qkv[6000 + i]; }
    __syncthreads();
    if (t < 400) {
      int i = t / 20, j = t % 20;
      float acc = 0.f;
      for (int d = 0; d < 300; ++d) acc += A[i*300 + d] * Bs[j*300 + d];
      att[t] = acc * 0.05773502691896258f;  // 1/sqrt(300)
    }
    __syncthreads();
    if (t < 20) {
      float m = -1e30f;
      for (int j = 0; j < 20; ++j) m = fmaxf(m, att[t*20 + j]);
      float s = 0.f;
      for (int j = 0; j < 20; ++j) { float e = __expf(att[t*20 + j] - m); att[t*20 + j] = e; s += e; }
      float inv = 1.f / s;
      for (int j = 0; j < 20; ++j) att[t*20 + j] *= inv;
    }
    __syncthreads();
    if (t < 20) {
      float s = 0.f;
      for (int i = 0; i < 20; ++i) s += att[i*20 + t];
      wsum[t] = s * 0.05f;
    }
    __syncthreads();
    if (t < 300) {
      const float* v = qkv + 12000;
      float acc = 0.f;
      for (int j = 0; j < 20; ++j) acc += wsum[j] * v[j*300 + t];
      n1g[t] = acc;
    }
    return;
  }
  if (blockIdx.x == 1) {                 // ---- adjn / rsA / AE1 ----
    float* drt = sp;           // 20
    float* an  = sp + 32;      // 400
    if (t < 20) {
      float s = 1.f;
      for (int j = 0; j < 20; ++j) s += adj[t*20 + j];
      drt[t] = rsqrtf(s);
    }
    __syncthreads();
    if (t < 400) {
      int i = t / 20, j = t % 20;
      float a = adj[t] + (i == j ? 1.f : 0.f);
      float v = drt[i] * a * drt[j];
      an[t] = v;
      adjng[t] = v;
    }
    __syncthreads();
    if (t < 20) {
      float s = 0.f;
      for (int m = 0; m < 20; ++m) s += an[t*20 + m];
      rsAg[t] = s;
    }
    if (t < 256) {
      float e[20];
      #pragma unroll
      for (int m = 0; m < 20; ++m) e[m] = E1[m*256 + t];
      for (int n = 0; n < 20; ++n) {
        float acc = 0.f;
        #pragma unroll
        for (int m = 0; m < 20; ++m) acc += an[n*20 + m] * e[m];
        AE1g[n*256 + t] = acc;
      }
    }
    return;
  }
  // ---- dgm + fmax/cmax reduce, b = blockIdx.x-2 ----
  int b = blockIdx.x - 2;
  float* xm = sp;            // 256
  float* redm = xm + 256;    // 8
  float* reds = redm + 8;    // 8
  if (t < 256) {
    float s = 0.f;
    #pragma unroll
    for (int r = 0; r < 8; ++r) s += xsump[(b*8 + r)*256 + t];
    xm[t] = s * (1.f / 1024.f);
  }
  if (t >= 256 && t < 272) {
    int m = t - 256; float fm = 0.f;
    for (int r = 0; r < 8; ++r) fm = fmaxf(fm, fmaxp[b*128 + r*16 + m]);
    fmaxb[b*16 + m] = fm;
  }
  if (t == 272) {
    float cm = 0.f;
    for (int r = 0; r < 8; ++r) cm = fmaxf(cm, cmaxp[b*8 + r]);
    cmaxb[b] = cm;
  }
  __syncthreads();
  if (t < 16) {
    float g = 0.f;
    for (int c = 0; c < 256; ++c) g += glob_w[t*256 + c] * xm[c];
    dgd[b*16 + t] = 0.5f * tanhf(0.5f * g);   // sigmoid(g) - 0.5
  }
  float v0 = s_raw[b*1024 + t], v1 = s_raw[b*1024 + 512 + t];
  float m = fmaxf(v0, v1);
  #pragma unroll
  for (int off = 32; off; off >>= 1) m = fmaxf(m, __shfl_xor(m, off, 64));
  int wv = t >> 6, ll = t & 63;
  if (ll == 0) redm[wv] = m;
  __syncthreads();
  float bm = redm[0];
  #pragma unroll
  for (int i = 1; i < 8; ++i) bm = fmaxf(bm, redm[i]);
  float e0 = __expf(v0 - bm), e1 = __expf(v1 - bm);
  float s2 = e0 + e1;
  #pragma unroll
  for (int off = 32; off; off >>= 1) s2 += __shfl_xor(s2, off, 64);
  if (ll == 0) reds[wv] = s2;
  __syncthreads();
  float tot = 0.f;
  #pragma unroll
  for (int i = 0; i < 8; ++i) tot += reds[i];
  float inv = 1.f / tot;
  mcol[b*1024 + t]       = e0 * inv;
  mcol[b*1024 + 512 + t] = e1 * inv;
}

// =================== LAUNCH C: k_w1 (38 blocks) ===================
// w1part[i][c] = sum_{d in [8i, 8i+8) ∩ [0,300)} n1[d] * WG1[d][c]
__global__ __launch_bounds__(256) void k_w1(const float* n1g, const float* WG1,
                                            float* w1part) {
  int t = threadIdx.x, i = blockIdx.x, d0 = i*8;
  float acc = 0.f;
  #pragma unroll
  for (int k = 0; k < 8; ++k) {
    int d = d0 + k;
    if (d < 300) acc += n1g[d] * WG1[d*256 + t];
  }
  w1part[i*256 + t] = acc;
}

// =================== LAUNCH D: k_gu (32 blocks, 8-col slices) ===================
__global__ __launch_bounds__(256) void k_gu(const float* w1part,
    const float* bg1, const float* AE1g, const float* rsAg, const float* adjng,
    const float* gc2_w, const float* final_w, float* upart) {
  __shared__ float adjns[400], rsAs[32], w1s[256], h2s[176], rgs[8];
  __shared__ float g1s[20*260];   // rows padded to 260
  __shared__ float gs2[2048];     // [256 d][8 cl]
  int t = threadIdx.x, c0 = blockIdx.x * 8;
  for (int i = t; i < 400; i += 256) adjns[i] = adjng[i];
  if (t < 20) rsAs[t] = rsAg[t];
  #pragma unroll
  for (int k2 = 0; k2 < 8; ++k2) {       // stage gc2 slice (independent loads)
    int idx = k2*256 + t, d = idx >> 3, cl = idx & 7;
    gs2[idx] = gc2_w[d*256 + c0 + cl];
  }
  {                                      // w1 = bg1 + sum of partials
    float acc = bg1[t];
    #pragma unroll
    for (int i = 0; i < 38; ++i) acc += w1part[i*256 + t];
    w1s[t] = acc;
  }
  float ae[20];
  #pragma unroll
  for (int k2 = 0; k2 < 20; ++k2) ae[k2] = AE1g[k2*256 + t];
  __syncthreads();
  #pragma unroll
  for (int k2 = 0; k2 < 20; ++k2)
    g1s[k2*260 + t] = fmaxf(ae[k2] + rsAs[k2] * w1s[t], 0.f);
  __syncthreads();
  int cl = t & 7, n = t >> 3;            // n 0..32, use n<20
  if (n < 20) {
    float acc = 0.f;
    for (int d = 0; d < 256; ++d) acc += g1s[n*260 + d] * gs2[d*8 + cl];
    h2s[n*8 + cl] = acc;
  }
  __syncthreads();
  if (t < 8) {
    float rga = 0.f;
    for (int nn = 0; nn < 20; ++nn) {
      float a2 = 0.f;
      #pragma unroll
      for (int m = 0; m < 20; ++m) a2 += adjns[nn*20 + m] * h2s[m*8 + t];
      rga += fmaxf(a2, 0.f);
    }
    rgs[t] = rga;
  }
  __syncthreads();
  {                                      // upart over this block's 8-k slice
    float acc = 0.f;
    const float* fw = final_w + t*512 + 256 + c0;
    #pragma unroll
    for (int kk = 0; kk < 8; ++kk) acc += fw[kk] * rgs[kk];
    upart[blockIdx.x*256 + t] = acc;
  }
}

// =================== LAUNCH E: k_main (p-tile 16, 4 blocks/CU) ===================
// Round-6 verified schedule re-parameterized: S[p,q] via MFMA + rank-1 term;
// E=exp(S-Mb); S2u += E @ x_r (PT dbuf, 2 st per barrier, prefetch 1 ahead);
// T = x_r - S2u/rs; out = relu(M@T^T + mcol*u + x).
// grid (64,16) = 1024 blocks -> 4/CU. Waves: S phase (ks=st-parity, qh=q-half);
// PV phase c-quarter = w*64.
__global__ __launch_bounds__(256) void k_main(const float* x, const bf16_t* fB,
    const bf16_t* fBT, const bf16_t* xT, const bf16_t* M16, const float* fmaxb,
    const float* mcol, const float* upart, const float* dgd, const float* csum,
    const float* cmaxb, float* out) {
  int flat = blockIdx.y * 64 + blockIdx.x;
  int b  = (flat & 7) * 2 + ((flat >> 3) >> 6);   // bijective XCD remap: 2 batches/XCD
  int p0 = ((flat >> 3) & 63) * 16;
  int t = threadIdx.x, w = t >> 6, l = t & 63, lr = l & 15, quad = l >> 4;
  int ks = w >> 1, qh = w & 1;
  __shared__ __align__(16) char smem[8448];   // union: {PT dbuf 2x(2x[16][40]) | e_s} / T_ls[16][264]
  bf16_t* PT0  = (bf16_t*)smem;               // 2 buf x 2 st-tiles x 640 elem
  bf16_t* e_s  = (bf16_t*)(smem + 5120);      // [16][40] (m>=16 zero)
  bf16_t* T_ls = (bf16_t*)smem;               // [16][264] phase 2
  __shared__ float Mb_s[16], fmax_s[16], u_s[256], rsinv_s[16], dgd_s[16];
  __shared__ float c_s[1024], ha_s[16], rs_s[4][16];
  const float*  xb   = x   + b*262144;
  const bf16_t* fBb  = fB  + b*16384;
  const bf16_t* fBTb = fBT + b*16384;
  const bf16_t* xTb  = xT  + b*262144;
  for (int i = t; i < 640; i += 256) e_s[i] = (bf16_t)0.f;
  {
    float us = 0.f;
    #pragma unroll
    for (int j = 0; j < 32; ++j) us += upart[j*256 + t];
    u_s[t] = us;
  }
  for (int i = t; i < 1024; i += 256) c_s[i] = csum[b*1024 + i];
  if (t < 16) { fmax_s[t] = fmaxb[b*16 + t]; dgd_s[t] = dgd[b*16 + t]; }
  __syncthreads();
  // e'[p,m] = x_phi * (sig(g[m])-0.5); one (p,m) per thread
  e_s[(t >> 4)*40 + (t & 15)] = (bf16_t)((float)fBb[p0*16 + t] * dgd_s[t & 15]);
  __syncthreads();
  if (t < 16) {
    float a = 0.f;
    #pragma unroll
    for (int m = 0; m < 16; ++m) a += (float)fBb[(p0 + t)*16 + m];
    float ha = 0.5f * a;
    ha_s[t] = ha;
    float mb = ha * cmaxb[b];
    #pragma unroll
    for (int m = 0; m < 16; ++m) mb += fmaxf((float)e_s[t*40 + m], 0.f) * fmax_s[m];
    Mb_s[t] = mb;  // exact upper bound on row max of S
  }
  __syncthreads();
  bf16x8 be = *(const bf16x8*)(e_s + lr*40 + quad*8);   // p = lr
  float mb_lane = Mb_s[lr];
  float ha_lane = ha_s[lr];
  float rs = 0.f;
  f32x4 acc[4];  // S2u[p = quad*4+r][c = w*64+cf*16+lr]
  #pragma unroll
  for (int j = 0; j < 4; ++j) acc[j] = (f32x4){0.f, 0.f, 0.f, 0.f};
  bf16x8 zer;
  #pragma unroll
  for (int j = 0; j < 8; ++j) zer[j] = (bf16_t)0.f;
  bf16x8 a0 = zer, a0n = zer;
  if (quad < 2) a0 = *(const bf16x8*)(fBTb + (ks*32 + qh*16 + lr)*16 + quad*8);
  const bf16_t* xrow = xTb + (w*64 + lr)*1024 + quad*8;
  bf16x8 bv[2][4], bvn[2][4];
  #pragma unroll
  for (int k = 0; k < 2; ++k)
    #pragma unroll
    for (int cf = 0; cf < 4; ++cf)
      bv[k][cf] = *(const bf16x8*)(xrow + cf*16384 + k*32);
  int cur = 0;
  for (int u2 = 0; u2 < 16; ++u2) {
    int st = u2*2 + ks;
    f32x4 z = {0.f, 0.f, 0.f, 0.f};
    f32x4 s0 = MFMA(a0, be, z);   // D[q = st*32 + qh*16 + quad*4+r][p = lr]
    if (u2 < 15) {                // prefetch next super-iter
      if (quad < 2)
        a0n = *(const bf16x8*)(fBTb + (((u2 + 1)*2 + ks)*32 + qh*16 + lr)*16 + quad*8);
      #pragma unroll
      for (int k = 0; k < 2; ++k)
        #pragma unroll
        for (int cf = 0; cf < 4; ++cf)
          bvn[k][cf] = *(const bf16x8*)(xrow + cf*16384 + (u2*2 + 2 + k)*32);
    }
    bf16_t* PTc = PT0 + cur*1280;
    bf16x4 pv;
    #pragma unroll
    for (int r = 0; r < 4; ++r) {
      float S0 = s0[r] + ha_lane * c_s[st*32 + qh*16 + quad*4 + r];
      float E0 = __expf(S0 - mb_lane);
      rs += E0; pv[r] = (bf16_t)E0;
    }
    *(bf16x4*)(PTc + ks*640 + lr*40 + qh*16 + quad*4) = pv;
    __syncthreads();
    bf16x8 ap0 = *(const bf16x8*)(PTc + lr*40 + quad*8);          // E[p=lr][q of st 2u2]
    bf16x8 ap1 = *(const bf16x8*)(PTc + 640 + lr*40 + quad*8);    // st 2u2+1
    #pragma unroll
    for (int cf = 0; cf < 4; ++cf) {
      acc[cf] = MFMA(ap0, bv[0][cf], acc[cf]);
      acc[cf] = MFMA(ap1, bv[1][cf], acc[cf]);
    }
    if (u2 < 15) {
      a0 = a0n;
      #pragma unroll
      for (int k = 0; k < 2; ++k)
        #pragma unroll
        for (int cf = 0; cf < 4; ++cf) bv[k][cf] = bvn[k][cf];
    }
    cur ^= 1;
  }
  rs += __shfl_xor(rs, 16, 64);
  rs += __shfl_xor(rs, 32, 64);          // per-wave partial rowsum for p = lr
  if (l < 16) rs_s[w][l] = rs;
  __syncthreads();   // rs staged; all PT/e_s reads drained -> T_ls may overwrite
  if (t < 16) rsinv_s[t] =
      1.f / fmaxf(rs_s[0][t] + rs_s[1][t] + rs_s[2][t] + rs_s[3][t], 1e-30f);
  __syncthreads();
  #pragma unroll
  for (int cf = 0; cf < 4; ++cf)
    #pragma unroll
    for (int r = 0; r < 4; ++r) {
      int p = quad*4 + r;
      int c = w*64 + cf*16 + lr;
      float tv = xb[(p0 + p)*256 + c] - acc[cf][r] * rsinv_s[p];
      T_ls[p*264 + c] = (bf16_t)tv;    // spiral[p][c]
    }
  __syncthreads();
  f32x4 acc2[4];  // D2[o = w*64+of*16+quad*4+r][p = lr]
  #pragma unroll
  for (int i = 0; i < 4; ++i) acc2[i] = (f32x4){0.f, 0.f, 0.f, 0.f};
  for (int c0 = 0; c0 < 256; c0 += 32) {
    bf16x8 am[4];
    #pragma unroll
    for (int of = 0; of < 4; ++of)
      am[of] = *(const bf16x8*)(M16 + (w*64 + of*16 + lr)*256 + c0 + quad*8);
    bf16x8 bt = *(const bf16x8*)(T_ls + lr*264 + c0 + quad*8);
    #pragma unroll
    for (int of = 0; of < 4; ++of) acc2[of] = MFMA(am[of], bt, acc2[of]);
  }
  float mc = mcol[b*1024 + p0 + lr];
  float* outb = out + b*262144;
  #pragma unroll
  for (int of = 0; of < 4; ++of)
    #pragma unroll
    for (int r = 0; r < 4; ++r) {
      int o = w*64 + of*16 + quad*4 + r;
      int pg = p0 + lr;
      float v = acc2[of][r] + mc * u_s[o] + xb[o*1024 + pg];
      outb[o*1024 + pg] = fmaxf(v, 0.f);
    }
}

// ---------------- launch ----------------

extern "C" void kernel_launch(void* const* d_in, const int* in_sizes, int n_in,
                              void* d_out, int out_size, void* d_ws, size_t ws_size,
                              hipStream_t stream) {
  (void)in_sizes; (void)n_in; (void)out_size; (void)ws_size;
  const float* x       = (const float*)d_in[0];
  const float* emb     = (const float*)d_in[1];
  const float* adj     = (const float*)d_in[2];
  const float* wq      = (const float*)d_in[3];
  const float* bq      = (const float*)d_in[4];
  const float* wk      = (const float*)d_in[5];
  const float* bk      = (const float*)d_in[6];
  const float* wv      = (const float*)d_in[7];
  const float* bv      = (const float*)d_in[8];
  const float* wo      = (const float*)d_in[9];
  const float* bo      = (const float*)d_in[10];
  const float* phi_w   = (const float*)d_in[11];
  const float* phi_b   = (const float*)d_in[12];
  const float* glob_w  = (const float*)d_in[13];
  const float* gc1_w   = (const float*)d_in[14];
  const float* gc2_w   = (const float*)d_in[15];
  const float* gw_w    = (const float*)d_in[16];
  const float* s2l_w   = (const float*)d_in[17];
  const float* final_w = (const float*)d_in[19];
  float* out = (float*)d_out;

  float* W = (float*)d_ws;
  float* qkv    = W + 0;        // 18000 -> 18048
  float* xsump  = W + 18048;    // 32768 -> 50816
  float* s_raw  = W + 50816;    // 16384 -> 67200
  float* mcol   = W + 67200;    // 16384 -> 83584
  float* fmaxb  = W + 83584;    // 256   -> 83840
  float* dgd    = W + 83840;    // 256   -> 84096
  float* csum   = W + 84096;    // 16384 -> 100480
  float* cmaxb  = W + 100480;   // 64    -> 100544
  float* fmaxp  = W + 100544;   // 2048  -> 102592
  float* cmaxp  = W + 102592;   // 128   -> 102720
  float* E1     = W + 102720;   // 5120  -> 107840
  float* WG1    = W + 107840;   // 76800 -> 184640
  float* bg1    = W + 184640;   // 256   -> 184896
  float* n1     = W + 184896;   // 320   -> 185216
  float* adjn   = W + 185216;   // 448   -> 185664
  float* rsA    = W + 185664;   // 64    -> 185728
  float* AE1    = W + 185728;   // 5120  -> 190848
  float* upart  = W + 190848;   // 8192  -> 199040
  float* w1part = W + 199040;   // 9728  -> 208768 floats (835072 B)
  bf16_t* M16 = (bf16_t*)((char*)d_ws + 851968);   // 128 KB
  bf16_t* fB  = (bf16_t*)((char*)d_ws + 983040);   // 512 KB (m-major raw)
  bf16_t* fBT = (bf16_t*)((char*)d_ws + 1507328);  // 512 KB (q-major)
  bf16_t* xT  = (bf16_t*)((char*)d_ws + 2031616);  // 8 MB  (x transposed bf16)
  // total ws usage ~9.95 MB

  k_front<<<1789, 256, 0, stream>>>(final_w, gw_w, emb, wq, bq, wk, bk, wv, bv, x,
                                    phi_w, phi_b, s2l_w, gc1_w, wo, bo,
                                    M16, qkv, fB, fBT, s_raw, xsump, csum,
                                    fmaxp, cmaxp, xT, E1, WG1, bg1);
  k_mid1<<<18, 512, 0, stream>>>(adj, qkv, E1, glob_w, xsump, s_raw,
                                 fmaxp, cmaxp,
                                 n1, adjn, rsA, AE1, dgd, mcol, fmaxb, cmaxb);
  k_w1<<<38, 256, 0, stream>>>(n1, WG1, w1part);
  k_gu<<<32, 256, 0, stream>>>(w1part, bg1, AE1, rsA, adjn, gc2_w, final_w, upart);
  k_main<<<dim3(64, 16), 256, 0, stream>>>(x, fB, fBT, xT, M16, fmaxb, mcol, upart,
                                           dgd, csum, cmaxb, out);
}

// Round 9
// 200.716 us; speedup vs baseline: 1.1872x; 1.1872x over previous
//
#include <hip/hip_runtime.h>
#include <hip/hip_bf16.h>

// Inputs/outputs are FLOAT32 (reference dtype). bf16 used only internally for MFMA.
typedef __bf16 bf16_t;
typedef bf16_t bf16x8 __attribute__((ext_vector_type(8)));
typedef bf16_t bf16x4 __attribute__((ext_vector_type(4)));
typedef float  f32x4  __attribute__((ext_vector_type(4)));

#define MFMA(a,b,c) __builtin_amdgcn_mfma_f32_16x16x32_bf16((a),(b),(c),0,0,0)

// =================== LAUNCH A: k_front (1789 blocks) ===================
// roles by blockIdx.x:
//   [0,256)     : M = final_w[:, :256] @ gw_w  (bf16)
//   [256,316)   : qkv = emb @ {wq,wk,wv} + bias
//   [316,444)   : phis (8 roles x 16 b): fB, fBT, s_raw, csum, fmax/cmax, xsump
//   [444,464)   : E1 = emb @ gc1_w  [20][256]
//   [464,765)   : WG1 = wo @ gc1_w [300][256]; row 300 = bg1 = bo @ gc1_w
//   [765,1789)  : xT transpose: raw [1024q][256c] fp32 -> xT [256c][1024q] bf16
__global__ __launch_bounds__(256) void k_front(
    const float* final_w, const float* gw_w, const float* emb,
    const float* wq, const float* bq, const float* wk, const float* bk,
    const float* wv, const float* bvv, const float* x,
    const float* phi_w, const float* phi_b, const float* s2l_w,
    const float* gc1_w, const float* wo, const float* bo,
    bf16_t* M16, float* qkv, bf16_t* fB, bf16_t* fBT, float* s_raw,
    float* xsump, float* csum, float* fmaxp, float* cmaxp, bf16_t* xT,
    float* E1, float* WG1, float* bg1) {
  __shared__ __align__(16) char sp[27648];
  int bid = blockIdx.x, t = threadIdx.x;
  if (bid < 256) {                       // ---- k_M ----
    float* fw = (float*)sp;
    int o = bid, c = t;
    fw[c] = final_w[o*512 + c];
    __syncthreads();
    float acc = 0.f;
    for (int k = 0; k < 256; ++k) acc += fw[k] * gw_w[k*256 + c];
    M16[o*256 + c] = (bf16_t)acc;
    return;
  }
  if (bid < 316) {                       // ---- k_qkv ----
    int id = bid - 256;
    int mat = id / 20, row = id % 20;
    const float* W  = mat == 0 ? wq : (mat == 1 ? wk : wv);
    const float* Bb = mat == 0 ? bq : (mat == 1 ? bk : bvv);
    float* er = (float*)sp;
    for (int i = t; i < 300; i += 256) er[i] = emb[row*300 + i];
    __syncthreads();
    for (int o = t; o < 300; o += 256) {
      float acc = Bb[o];
      for (int d = 0; d < 300; ++d) acc += er[d] * W[d*300 + o];
      qkv[(mat*20 + row)*300 + o] = acc;
    }
    return;
  }
  if (bid < 444) {                       // ---- k_phis ----
    int id = bid - 316;
    int b = id >> 3, role = id & 7;
    const float* xb = x + b*262144;
    float* pw = (float*)sp;              // 4096
    float* wi = pw + 4096;               // 256
    float* pb = wi + 256;                // 16
    float* phs = pb + 16;                // [128][18]
    unsigned* fmu = (unsigned*)(phs + 2304);  // 16
    unsigned* cmu = fmu + 16;            // 1
    for (int i = t; i < 4096; i += 256) pw[i] = phi_w[i];
    wi[t] = s2l_w[t];
    if (t < 16) { pb[t] = phi_b[t]; fmu[t] = 0u; }
    if (t == 0) cmu[0] = 0u;
    __syncthreads();
    int hwl = t & 127, half = t >> 7;
    int hw = role*128 + hwl;
    float ph[16];
    #pragma unroll
    for (int o = 0; o < 16; ++o) ph[o] = 0.f;
    float sacc = 0.f;
    for (int ci = 0; ci < 128; ++ci) {
      int c = half*128 + ci;
      float xv = xb[c*1024 + hw];
      sacc += wi[c] * xv;
      #pragma unroll
      for (int o = 0; o < 16; ++o) ph[o] += pw[o*256 + c] * xv;
    }
    if (half == 0) {
      #pragma unroll
      for (int o = 0; o < 16; ++o) phs[hwl*18 + o] = ph[o];
      phs[hwl*18 + 16] = sacc;
    }
    __syncthreads();
    if (half == 1) {
      #pragma unroll
      for (int o = 0; o < 16; ++o) phs[hwl*18 + o] += ph[o];
      s_raw[b*1024 + hw] = phs[hwl*18 + 16] + sacc;
    }
    __syncthreads();
    float csacc = 0.f;
    #pragma unroll
    for (int i = 0; i < 8; ++i) {
      int j = i*256 + t;
      int o = j >> 7, hl = j & 127;
      float val = fmaxf(phs[hl*18 + o] + pb[o], 0.f);
      bf16_t bv16 = (bf16_t)val;
      atomicMax(&fmu[o], __float_as_uint((float)bv16));
      fB [b*16384 + o*1024 + role*128 + hl] = bv16;            // m-major (raw)
      fBT[b*16384 + (role*128 + hl)*16 + o] = bv16;            // q-major
      csacc += (float)bv16;
    }
    if (half == 0) phs[hwl*18 + 17] = csacc;
    __syncthreads();
    if (half == 1) {
      float cs = phs[hwl*18 + 17] + csacc;
      csum[b*1024 + hw] = cs;
      atomicMax(cmu, __float_as_uint(cs));
    }
    if (t < 16) fmaxp[b*128 + role*16 + t] = __uint_as_float(fmu[t]);
    __syncthreads();
    if (t == 0) cmaxp[b*8 + role] = __uint_as_float(cmu[0]);
    // xsum partial for this (b, role): L2-hot re-read, thread owns channel c = t
    {
      const f32x4* xr = (const f32x4*)(xb + t*1024 + role*128);
      float s4 = 0.f;
      #pragma unroll
      for (int j = 0; j < 32; ++j) { f32x4 v = xr[j]; s4 += v[0] + v[1] + v[2] + v[3]; }
      xsump[(b*8 + role)*256 + t] = s4;
    }
    return;
  }
  if (bid < 464) {                       // ---- E1 = emb @ gc1_w ----
    int n = bid - 444;
    float* er = (float*)sp;
    for (int i = t; i < 300; i += 256) er[i] = emb[n*300 + i];
    __syncthreads();
    float acc = 0.f;
    for (int d = 0; d < 300; ++d) acc += er[d] * gc1_w[d*256 + t];
    E1[n*256 + t] = acc;
    return;
  }
  if (bid < 765) {                       // ---- WG1 rows / bg1 ----
    int d0 = bid - 464;                  // 0..300
    float* er = (float*)sp;
    if (d0 < 300) { for (int i = t; i < 300; i += 256) er[i] = wo[d0*300 + i]; }
    else          { for (int i = t; i < 300; i += 256) er[i] = bo[i]; }
    __syncthreads();
    float acc = 0.f;
    for (int e = 0; e < 300; ++e) acc += er[e] * gc1_w[e*256 + t];
    if (d0 < 300) WG1[d0*256 + t] = acc; else bg1[t] = acc;
    return;
  }
  {                                      // ---- k_xt: raw-reshape transpose ----
    int id = bid - 765;                  // 0..1023
    int bb = id >> 6, tile = id & 63;
    int q0 = (tile >> 2) * 64, c0 = (tile & 3) * 64;
    bf16_t* tl = (bf16_t*)sp;            // [64][74]
    const float* xbb = x + bb*262144;
    #pragma unroll
    for (int k = 0; k < 16; ++k) {
      int idx = k*256 + t, qi = idx >> 6, ci = idx & 63;
      tl[ci*74 + qi] = (bf16_t)xbb[(q0 + qi)*256 + c0 + ci];
    }
    __syncthreads();
    #pragma unroll
    for (int k = 0; k < 16; ++k) {
      int idx = k*256 + t, ci = idx >> 6, qi = idx & 63;
      xT[bb*262144 + (c0 + ci)*1024 + q0 + qi] = tl[ci*74 + qi];
    }
    return;
  }
}

// =================== LAUNCH B: k_mid1 (18 blocks x 512) ===================
__global__ __launch_bounds__(512) void k_mid1(
    const float* adj, const float* qkv, const float* E1,
    const float* glob_w, const float* xsump, const float* s_raw,
    const float* fmaxp, const float* cmaxp,
    float* n1g, float* adjng, float* rsAg, float* AE1g,
    float* dgd, float* mcol, float* fmaxb, float* cmaxb) {
  __shared__ __align__(16) float sp[12480];
  int t = threadIdx.x;
  if (blockIdx.x == 0) {                 // ---- attention -> n1 ----
    float* A  = sp;            // 6000 q
    float* Bs = A + 6000;      // 6000 k
    float* att  = Bs + 6000;   // 400
    float* wsum = att + 400;   // 20
    for (int i = t; i < 6000; i += 512) { A[i] = qkv[i]; Bs[i] = qkv[6000 + i]; }
    __syncthreads();
    if (t < 400) {
      int i = t / 20, j = t % 20;
      float acc = 0.f;
      for (int d = 0; d < 300; ++d) acc += A[i*300 + d] * Bs[j*300 + d];
      att[t] = acc * 0.05773502691896258f;  // 1/sqrt(300)
    }
    __syncthreads();
    if (t < 20) {
      float m = -1e30f;
      for (int j = 0; j < 20; ++j) m = fmaxf(m, att[t*20 + j]);
      float s = 0.f;
      for (int j = 0; j < 20; ++j) { float e = __expf(att[t*20 + j] - m); att[t*20 + j] = e; s += e; }
      float inv = 1.f / s;
      for (int j = 0; j < 20; ++j) att[t*20 + j] *= inv;
    }
    __syncthreads();
    if (t < 20) {
      float s = 0.f;
      for (int i = 0; i < 20; ++i) s += att[i*20 + t];
      wsum[t] = s * 0.05f;
    }
    __syncthreads();
    if (t < 300) {
      const float* v = qkv + 12000;
      float acc = 0.f;
      for (int j = 0; j < 20; ++j) acc += wsum[j] * v[j*300 + t];
      n1g[t] = acc;
    }
    return;
  }
  if (blockIdx.x == 1) {                 // ---- adjn / rsA / AE1 ----
    float* drt = sp;           // 20
    float* an  = sp + 32;      // 400
    if (t < 20) {
      float s = 1.f;
      for (int j = 0; j < 20; ++j) s += adj[t*20 + j];
      drt[t] = rsqrtf(s);
    }
    __syncthreads();
    if (t < 400) {
      int i = t / 20, j = t % 20;
      float a = adj[t] + (i == j ? 1.f : 0.f);
      float v = drt[i] * a * drt[j];
      an[t] = v;
      adjng[t] = v;
    }
    __syncthreads();
    if (t < 20) {
      float s = 0.f;
      for (int m = 0; m < 20; ++m) s += an[t*20 + m];
      rsAg[t] = s;
    }
    if (t < 256) {
      float e[20];
      #pragma unroll
      for (int m = 0; m < 20; ++m) e[m] = E1[m*256 + t];
      for (int n = 0; n < 20; ++n) {
        float acc = 0.f;
        #pragma unroll
        for (int m = 0; m < 20; ++m) acc += an[n*20 + m] * e[m];
        AE1g[n*256 + t] = acc;
      }
    }
    return;
  }
  // ---- dgm + fmax/cmax reduce, b = blockIdx.x-2 ----
  int b = blockIdx.x - 2;
  float* xm = sp;            // 256
  float* redm = xm + 256;    // 8
  float* reds = redm + 8;    // 8
  if (t < 256) {
    float s = 0.f;
    #pragma unroll
    for (int r = 0; r < 8; ++r) s += xsump[(b*8 + r)*256 + t];
    xm[t] = s * (1.f / 1024.f);
  }
  if (t >= 256 && t < 272) {
    int m = t - 256; float fm = 0.f;
    for (int r = 0; r < 8; ++r) fm = fmaxf(fm, fmaxp[b*128 + r*16 + m]);
    fmaxb[b*16 + m] = fm;
  }
  if (t == 272) {
    float cm = 0.f;
    for (int r = 0; r < 8; ++r) cm = fmaxf(cm, cmaxp[b*8 + r]);
    cmaxb[b] = cm;
  }
  __syncthreads();
  if (t < 16) {
    float g = 0.f;
    for (int c = 0; c < 256; ++c) g += glob_w[t*256 + c] * xm[c];
    dgd[b*16 + t] = 0.5f * tanhf(0.5f * g);   // sigmoid(g) - 0.5
  }
  float v0 = s_raw[b*1024 + t], v1 = s_raw[b*1024 + 512 + t];
  float m = fmaxf(v0, v1);
  #pragma unroll
  for (int off = 32; off; off >>= 1) m = fmaxf(m, __shfl_xor(m, off, 64));
  int wv = t >> 6, ll = t & 63;
  if (ll == 0) redm[wv] = m;
  __syncthreads();
  float bm = redm[0];
  #pragma unroll
  for (int i = 1; i < 8; ++i) bm = fmaxf(bm, redm[i]);
  float e0 = __expf(v0 - bm), e1 = __expf(v1 - bm);
  float s2 = e0 + e1;
  #pragma unroll
  for (int off = 32; off; off >>= 1) s2 += __shfl_xor(s2, off, 64);
  if (ll == 0) reds[wv] = s2;
  __syncthreads();
  float tot = 0.f;
  #pragma unroll
  for (int i = 0; i < 8; ++i) tot += reds[i];
  float inv = 1.f / tot;
  mcol[b*1024 + t]       = e0 * inv;
  mcol[b*1024 + 512 + t] = e1 * inv;
}

// =================== LAUNCH C: k_w1 (38 blocks) ===================
// w1part[i][c] = sum_{d in [8i, 8i+8) ∩ [0,300)} n1[d] * WG1[d][c]
__global__ __launch_bounds__(256) void k_w1(const float* n1g, const float* WG1,
                                            float* w1part) {
  int t = threadIdx.x, i = blockIdx.x, d0 = i*8;
  float acc = 0.f;
  #pragma unroll
  for (int k = 0; k < 8; ++k) {
    int d = d0 + k;
    if (d < 300) acc += n1g[d] * WG1[d*256 + t];
  }
  w1part[i*256 + t] = acc;
}

// =================== LAUNCH D: k_gu (32 blocks, 8-col slices) ===================
__global__ __launch_bounds__(256) void k_gu(const float* w1part,
    const float* bg1, const float* AE1g, const float* rsAg, const float* adjng,
    const float* gc2_w, const float* final_w, float* upart) {
  __shared__ float adjns[400], rsAs[32], w1s[256], h2s[176], rgs[8];
  __shared__ float g1s[20*260];   // rows padded to 260
  __shared__ float gs2[2048];     // [256 d][8 cl]
  int t = threadIdx.x, c0 = blockIdx.x * 8;
  for (int i = t; i < 400; i += 256) adjns[i] = adjng[i];
  if (t < 20) rsAs[t] = rsAg[t];
  #pragma unroll
  for (int k2 = 0; k2 < 8; ++k2) {       // stage gc2 slice (independent loads)
    int idx = k2*256 + t, d = idx >> 3, cl = idx & 7;
    gs2[idx] = gc2_w[d*256 + c0 + cl];
  }
  {                                      // w1 = bg1 + sum of partials
    float acc = bg1[t];
    #pragma unroll
    for (int i = 0; i < 38; ++i) acc += w1part[i*256 + t];
    w1s[t] = acc;
  }
  float ae[20];
  #pragma unroll
  for (int k2 = 0; k2 < 20; ++k2) ae[k2] = AE1g[k2*256 + t];
  __syncthreads();
  #pragma unroll
  for (int k2 = 0; k2 < 20; ++k2)
    g1s[k2*260 + t] = fmaxf(ae[k2] + rsAs[k2] * w1s[t], 0.f);
  __syncthreads();
  int cl = t & 7, n = t >> 3;            // n 0..32, use n<20
  if (n < 20) {
    float acc = 0.f;
    for (int d = 0; d < 256; ++d) acc += g1s[n*260 + d] * gs2[d*8 + cl];
    h2s[n*8 + cl] = acc;
  }
  __syncthreads();
  if (t < 8) {
    float rga = 0.f;
    for (int nn = 0; nn < 20; ++nn) {
      float a2 = 0.f;
      #pragma unroll
      for (int m = 0; m < 20; ++m) a2 += adjns[nn*20 + m] * h2s[m*8 + t];
      rga += fmaxf(a2, 0.f);
    }
    rgs[t] = rga;
  }
  __syncthreads();
  {                                      // upart over this block's 8-k slice
    float acc = 0.f;
    const float* fw = final_w + t*512 + 256 + c0;
    #pragma unroll
    for (int kk = 0; kk < 8; ++kk) acc += fw[kk] * rgs[kk];
    upart[blockIdx.x*256 + t] = acc;
  }
}

// =================== LAUNCH E: k_main (round-6 verified: p-tile 32) ===================
// S[p,q] = sum_m e'[p,m] f[m,q] (MFMA) + 0.5*a[p]*c[q]; E=exp(S-Mb); rowsum;
// S2u += E @ x_r; T = x_r - S2u/rs; out = relu(M@T^T + mcol*u + x).
// p-tile 32, grid (32,16) = 512 blocks (2/CU), XCD remap (2 batches/XCD).
// 2 st per barrier (16 barriers); bv/a0 prefetched one super-iter ahead.
__global__ __launch_bounds__(256) void k_main(const float* x, const bf16_t* fB,
    const bf16_t* fBT, const bf16_t* xT, const bf16_t* M16, const float* fmaxb,
    const float* mcol, const float* upart, const float* dgd, const float* csum,
    const float* cmaxb, float* out) {
  int flat = blockIdx.y * 32 + blockIdx.x;
  int b  = (flat & 7) * 2 + ((flat >> 3) >> 5);   // bijective XCD remap
  int p0 = ((flat >> 3) & 31) * 32;
  int t = threadIdx.x, w = t >> 6, l = t & 63, lr = l & 15, quad = l >> 4;
  int qh = w >> 1, ph = w & 1;
  __shared__ __align__(16) char smem[16896];       // union: {PT dbuf(2x2 tiles) | e_s} / T_ls
  bf16_t* PT0  = (bf16_t*)smem;                    // 2 buf x 2 tiles x [32][40]
  bf16_t* e_s  = (bf16_t*)(smem + 10240);          // [32][40] (m>=16 zero)
  bf16_t* T_ls = (bf16_t*)smem;                    // [32][264] phase 2
  __shared__ float Mb_s[32], fmax_s[16], u_s[256], rsinv_s[32], dgd_s[16];
  __shared__ float c_s[1024], ha_s[32], rs_s[2][32];
  const float*  xb   = x   + b*262144;
  const bf16_t* fBb  = fB  + b*16384;
  const bf16_t* fBTb = fBT + b*16384;
  const bf16_t* xTb  = xT  + b*262144;
  for (int i = t; i < 1280; i += 256) e_s[i] = (bf16_t)0.f;
  {
    float us = 0.f;
    #pragma unroll
    for (int j = 0; j < 32; ++j) us += upart[j*256 + t];
    u_s[t] = us;
  }
  for (int i = t; i < 1024; i += 256) c_s[i] = csum[b*1024 + i];
  if (t < 16) { fmax_s[t] = fmaxb[b*16 + t]; dgd_s[t] = dgd[b*16 + t]; }
  __syncthreads();
  for (int i = t; i < 512; i += 256) {       // e'[p,m] = x_phi * (sig(g[m])-0.5)
    int p = i >> 4, m = i & 15;
    e_s[p*40 + m] = (bf16_t)((float)fBb[p0*16 + i] * dgd_s[m]);
  }
  __syncthreads();
  if (t < 32) {
    float a = 0.f;
    #pragma unroll
    for (int m = 0; m < 16; ++m) a += (float)fBb[(p0 + t)*16 + m];
    float ha = 0.5f * a;
    ha_s[t] = ha;
    float mb = ha * cmaxb[b];
    #pragma unroll
    for (int m = 0; m < 16; ++m) mb += fmaxf((float)e_s[t*40 + m], 0.f) * fmax_s[m];
    Mb_s[t] = mb;  // exact upper bound on row max of S
  }
  __syncthreads();
  bf16x8 be = *(const bf16x8*)(e_s + (ph*16 + lr)*40 + quad*8);
  float mb_lane = Mb_s[ph*16 + lr];
  float ha_lane = ha_s[ph*16 + lr];
  float rs = 0.f;
  f32x4 acc[2][4];  // S2u[p = pf*16+quad*4+r][c = w*64+cf*16+lr]
  #pragma unroll
  for (int i = 0; i < 2; ++i)
    #pragma unroll
    for (int j = 0; j < 4; ++j) acc[i][j] = (f32x4){0.f, 0.f, 0.f, 0.f};
  bf16x8 zer;
  #pragma unroll
  for (int j = 0; j < 8; ++j) zer[j] = (bf16_t)0.f;
  bf16x8 a0[2], a0n[2];
  a0[0] = a0[1] = a0n[0] = a0n[1] = zer;
  if (quad < 2) {
    a0[0] = *(const bf16x8*)(fBTb + (qh*16 + lr)*16 + quad*8);
    a0[1] = *(const bf16x8*)(fBTb + (32 + qh*16 + lr)*16 + quad*8);
  }
  const bf16_t* xrow = xTb + (w*64 + lr)*1024 + quad*8;
  bf16x8 bv[2][4], bvn[2][4];
  #pragma unroll
  for (int k = 0; k < 2; ++k)
    #pragma unroll
    for (int cf = 0; cf < 4; ++cf)
      bv[k][cf] = *(const bf16x8*)(xrow + cf*16384 + k*32);
  int cur = 0;
  for (int u2 = 0; u2 < 16; ++u2) {
    f32x4 z = {0.f, 0.f, 0.f, 0.f};
    f32x4 s0 = MFMA(a0[0], be, z);   // D[q=(2u2)*32+qh*16+quad*4+r][p=ph*16+lr]
    f32x4 s1 = MFMA(a0[1], be, z);   // st 2u2+1
    if (u2 < 15) {                   // prefetch next super-iter (lands during barrier)
      if (quad < 2) {
        a0n[0] = *(const bf16x8*)(fBTb + ((u2*2 + 2)*32 + qh*16 + lr)*16 + quad*8);
        a0n[1] = *(const bf16x8*)(fBTb + ((u2*2 + 3)*32 + qh*16 + lr)*16 + quad*8);
      }
      #pragma unroll
      for (int k = 0; k < 2; ++k)
        #pragma unroll
        for (int cf = 0; cf < 4; ++cf)
          bvn[k][cf] = *(const bf16x8*)(xrow + cf*16384 + (u2*2 + 2 + k)*32);
    }
    bf16_t* PTc = PT0 + cur*2560;
    bf16x4 pv0, pv1;
    #pragma unroll
    for (int r = 0; r < 4; ++r) {
      float S0 = s0[r] + ha_lane * c_s[(u2*2)*32 + qh*16 + quad*4 + r];
      float E0 = __expf(S0 - mb_lane);
      rs += E0; pv0[r] = (bf16_t)E0;
      float S1 = s1[r] + ha_lane * c_s[(u2*2 + 1)*32 + qh*16 + quad*4 + r];
      float E1v = __expf(S1 - mb_lane);
      rs += E1v; pv1[r] = (bf16_t)E1v;
    }
    *(bf16x4*)(PTc + (ph*16 + lr)*40 + qh*16 + quad*4)        = pv0;
    *(bf16x4*)(PTc + 1280 + (ph*16 + lr)*40 + qh*16 + quad*4) = pv1;
    __syncthreads();
    #pragma unroll
    for (int k = 0; k < 2; ++k) {
      bf16x8 ap0 = *(const bf16x8*)(PTc + k*1280 + lr*40 + quad*8);
      bf16x8 ap1 = *(const bf16x8*)(PTc + k*1280 + (16 + lr)*40 + quad*8);
      #pragma unroll
      for (int cf = 0; cf < 4; ++cf) {
        acc[0][cf] = MFMA(ap0, bv[k][cf], acc[0][cf]);
        acc[1][cf] = MFMA(ap1, bv[k][cf], acc[1][cf]);
      }
    }
    if (u2 < 15) {
      #pragma unroll
      for (int k = 0; k < 2; ++k) {
        a0[k] = a0n[k];
        #pragma unroll
        for (int cf = 0; cf < 4; ++cf) bv[k][cf] = bvn[k][cf];
      }
    }
    cur ^= 1;
  }
  rs += __shfl_xor(rs, 16, 64);
  rs += __shfl_xor(rs, 32, 64);          // qh-half rowsum for p = ph*16+lr
  if (l < 16) rs_s[qh][ph*16 + lr] = rs;
  __syncthreads();   // rs staged; all PT/e_s reads drained -> T_ls may overwrite
  if (t < 32) rsinv_s[t] = 1.f / fmaxf(rs_s[0][t] + rs_s[1][t], 1e-30f);
  __syncthreads();
  #pragma unroll
  for (int pf = 0; pf < 2; ++pf)
    #pragma unroll
    for (int cf = 0; cf < 4; ++cf)
      #pragma unroll
      for (int r = 0; r < 4; ++r) {
        int p = pf*16 + quad*4 + r;
        int c = w*64 + cf*16 + lr;
        float tv = xb[(p0 + p)*256 + c] - acc[pf][cf][r] * rsinv_s[p];
        T_ls[p*264 + c] = (bf16_t)tv;    // spiral[p][c]
      }
  __syncthreads();
  f32x4 acc2[4][2];  // D2[o = w*64+of*16+quad*4+r][p = pf*16+lr]
  #pragma unroll
  for (int i = 0; i < 4; ++i)
    #pragma unroll
    for (int j = 0; j < 2; ++j) acc2[i][j] = (f32x4){0.f, 0.f, 0.f, 0.f};
  for (int c0 = 0; c0 < 256; c0 += 32) {
    bf16x8 am[4], bt[2];
    #pragma unroll
    for (int of = 0; of < 4; ++of)
      am[of] = *(const bf16x8*)(M16 + (w*64 + of*16 + lr)*256 + c0 + quad*8);
    #pragma unroll
    for (int pf = 0; pf < 2; ++pf)
      bt[pf] = *(const bf16x8*)(T_ls + (pf*16 + lr)*264 + c0 + quad*8);
    #pragma unroll
    for (int of = 0; of < 4; ++of)
      #pragma unroll
      for (int pf = 0; pf < 2; ++pf) acc2[of][pf] = MFMA(am[of], bt[pf], acc2[of][pf]);
  }
  float* outb = out + b*262144;
  #pragma unroll
  for (int of = 0; of < 4; ++of)
    #pragma unroll
    for (int pf = 0; pf < 2; ++pf)
      #pragma unroll
      for (int r = 0; r < 4; ++r) {
        int o = w*64 + of*16 + quad*4 + r;
        int pg = p0 + pf*16 + lr;
        float v = acc2[of][pf][r] + mcol[b*1024 + pg] * u_s[o] + xb[o*1024 + pg];
        outb[o*1024 + pg] = fmaxf(v, 0.f);
      }
}

// ---------------- launch ----------------

extern "C" void kernel_launch(void* const* d_in, const int* in_sizes, int n_in,
                              void* d_out, int out_size, void* d_ws, size_t ws_size,
                              hipStream_t stream) {
  (void)in_sizes; (void)n_in; (void)out_size; (void)ws_size;
  const float* x       = (const float*)d_in[0];
  const float* emb     = (const float*)d_in[1];
  const float* adj     = (const float*)d_in[2];
  const float* wq      = (const float*)d_in[3];
  const float* bq      = (const float*)d_in[4];
  const float* wk      = (const float*)d_in[5];
  const float* bk      = (const float*)d_in[6];
  const float* wv      = (const float*)d_in[7];
  const float* bv      = (const float*)d_in[8];
  const float* wo      = (const float*)d_in[9];
  const float* bo      = (const float*)d_in[10];
  const float* phi_w   = (const float*)d_in[11];
  const float* phi_b   = (const float*)d_in[12];
  const float* glob_w  = (const float*)d_in[13];
  const float* gc1_w   = (const float*)d_in[14];
  const float* gc2_w   = (const float*)d_in[15];
  const float* gw_w    = (const float*)d_in[16];
  const float* s2l_w   = (const float*)d_in[17];
  const float* final_w = (const float*)d_in[19];
  float* out = (float*)d_out;

  float* W = (float*)d_ws;
  float* qkv    = W + 0;        // 18000 -> 18048
  float* xsump  = W + 18048;    // 32768 -> 50816
  float* s_raw  = W + 50816;    // 16384 -> 67200
  float* mcol   = W + 67200;    // 16384 -> 83584
  float* fmaxb  = W + 83584;    // 256   -> 83840
  float* dgd    = W + 83840;    // 256   -> 84096
  float* csum   = W + 84096;    // 16384 -> 100480
  float* cmaxb  = W + 100480;   // 64    -> 100544
  float* fmaxp  = W + 100544;   // 2048  -> 102592
  float* cmaxp  = W + 102592;   // 128   -> 102720
  float* E1     = W + 102720;   // 5120  -> 107840
  float* WG1    = W + 107840;   // 76800 -> 184640
  float* bg1    = W + 184640;   // 256   -> 184896
  float* n1     = W + 184896;   // 320   -> 185216
  float* adjn   = W + 185216;   // 448   -> 185664
  float* rsA    = W + 185664;   // 64    -> 185728
  float* AE1    = W + 185728;   // 5120  -> 190848
  float* upart  = W + 190848;   // 8192  -> 199040
  float* w1part = W + 199040;   // 9728  -> 208768 floats (835072 B)
  bf16_t* M16 = (bf16_t*)((char*)d_ws + 851968);   // 128 KB
  bf16_t* fB  = (bf16_t*)((char*)d_ws + 983040);   // 512 KB (m-major raw)
  bf16_t* fBT = (bf16_t*)((char*)d_ws + 1507328);  // 512 KB (q-major)
  bf16_t* xT  = (bf16_t*)((char*)d_ws + 2031616);  // 8 MB  (x transposed bf16)
  // total ws usage ~9.95 MB

  k_front<<<1789, 256, 0, stream>>>(final_w, gw_w, emb, wq, bq, wk, bk, wv, bv, x,
                                    phi_w, phi_b, s2l_w, gc1_w, wo, bo,
                                    M16, qkv, fB, fBT, s_raw, xsump, csum,
                                    fmaxp, cmaxp, xT, E1, WG1, bg1);
  k_mid1<<<18, 512, 0, stream>>>(adj, qkv, E1, glob_w, xsump, s_raw,
                                 fmaxp, cmaxp,
                                 n1, adjn, rsA, AE1, dgd, mcol, fmaxb, cmaxb);
  k_w1<<<38, 256, 0, stream>>>(n1, WG1, w1part);
  k_gu<<<32, 256, 0, stream>>>(w1part, bg1, AE1, rsA, adjn, gc2_w, final_w, upart);
  k_main<<<dim3(32, 16), 256, 0, stream>>>(x, fB, fBT, xT, M16, fmaxb, mcol, upart,
                                           dgd, csum, cmaxb, out);
}

// Round 11
// 199.334 us; speedup vs baseline: 1.1954x; 1.0069x over previous
//
#include <hip/hip_runtime.h>
#include <hip/hip_bf16.h>

// Inputs/outputs are FLOAT32 (reference dtype). bf16 used only internally for MFMA.
typedef __bf16 bf16_t;
typedef bf16_t bf16x8 __attribute__((ext_vector_type(8)));
typedef bf16_t bf16x4 __attribute__((ext_vector_type(4)));
typedef float  f32x4  __attribute__((ext_vector_type(4)));

#define MFMA(a,b,c) __builtin_amdgcn_mfma_f32_16x16x32_bf16((a),(b),(c),0,0,0)
// T4 lean barrier: drain LDS only; global prefetches stay in flight across it.
#define LEAN_BARRIER() asm volatile("s_waitcnt lgkmcnt(0)\n\ts_barrier" ::: "memory")

// =================== LAUNCH A: k_front (1789 blocks) ===================
// roles by blockIdx.x:
//   [0,256)     : M = final_w[:, :256] @ gw_w  (bf16)
//   [256,316)   : qkv = emb @ {wq,wk,wv} + bias
//   [316,444)   : phis (8 roles x 16 b): fB, fBT, s_raw, csum, fmax/cmax, xsump
//   [444,464)   : E1 = emb @ gc1_w  [20][256]
//   [464,765)   : WG1 = wo @ gc1_w [300][256]; row 300 = bg1 = bo @ gc1_w
//   [765,1789)  : xT transpose: raw [1024q][256c] fp32 -> xT [256c][1024q] bf16
__global__ __launch_bounds__(256) void k_front(
    const float* final_w, const float* gw_w, const float* emb,
    const float* wq, const float* bq, const float* wk, const float* bk,
    const float* wv, const float* bvv, const float* x,
    const float* phi_w, const float* phi_b, const float* s2l_w,
    const float* gc1_w, const float* wo, const float* bo,
    bf16_t* M16, float* qkv, bf16_t* fB, bf16_t* fBT, float* s_raw,
    float* xsump, float* csum, float* fmaxp, float* cmaxp, bf16_t* xT,
    float* E1, float* WG1, float* bg1) {
  __shared__ __align__(16) char sp[27648];
  int bid = blockIdx.x, t = threadIdx.x;
  if (bid < 256) {                       // ---- k_M ----
    float* fw = (float*)sp;
    int o = bid, c = t;
    fw[c] = final_w[o*512 + c];
    __syncthreads();
    float acc = 0.f;
    for (int k = 0; k < 256; ++k) acc += fw[k] * gw_w[k*256 + c];
    M16[o*256 + c] = (bf16_t)acc;
    return;
  }
  if (bid < 316) {                       // ---- k_qkv ----
    int id = bid - 256;
    int mat = id / 20, row = id % 20;
    const float* W  = mat == 0 ? wq : (mat == 1 ? wk : wv);
    const float* Bb = mat == 0 ? bq : (mat == 1 ? bk : bvv);
    float* er = (float*)sp;
    for (int i = t; i < 300; i += 256) er[i] = emb[row*300 + i];
    __syncthreads();
    for (int o = t; o < 300; o += 256) {
      float acc = Bb[o];
      for (int d = 0; d < 300; ++d) acc += er[d] * W[d*300 + o];
      qkv[(mat*20 + row)*300 + o] = acc;
    }
    return;
  }
  if (bid < 444) {                       // ---- k_phis ----
    int id = bid - 316;
    int b = id >> 3, role = id & 7;
    const float* xb = x + b*262144;
    float* pw = (float*)sp;              // 4096
    float* wi = pw + 4096;               // 256
    float* pb = wi + 256;                // 16
    float* phs = pb + 16;                // [128][18]
    unsigned* fmu = (unsigned*)(phs + 2304);  // 16
    unsigned* cmu = fmu + 16;            // 1
    for (int i = t; i < 4096; i += 256) pw[i] = phi_w[i];
    wi[t] = s2l_w[t];
    if (t < 16) { pb[t] = phi_b[t]; fmu[t] = 0u; }
    if (t == 0) cmu[0] = 0u;
    __syncthreads();
    int hwl = t & 127, half = t >> 7;
    int hw = role*128 + hwl;
    float ph[16];
    #pragma unroll
    for (int o = 0; o < 16; ++o) ph[o] = 0.f;
    float sacc = 0.f;
    for (int ci = 0; ci < 128; ++ci) {
      int c = half*128 + ci;
      float xv = xb[c*1024 + hw];
      sacc += wi[c] * xv;
      #pragma unroll
      for (int o = 0; o < 16; ++o) ph[o] += pw[o*256 + c] * xv;
    }
    if (half == 0) {
      #pragma unroll
      for (int o = 0; o < 16; ++o) phs[hwl*18 + o] = ph[o];
      phs[hwl*18 + 16] = sacc;
    }
    __syncthreads();
    if (half == 1) {
      #pragma unroll
      for (int o = 0; o < 16; ++o) phs[hwl*18 + o] += ph[o];
      s_raw[b*1024 + hw] = phs[hwl*18 + 16] + sacc;
    }
    __syncthreads();
    float csacc = 0.f;
    #pragma unroll
    for (int i = 0; i < 8; ++i) {
      int j = i*256 + t;
      int o = j >> 7, hl = j & 127;
      float val = fmaxf(phs[hl*18 + o] + pb[o], 0.f);
      bf16_t bv16 = (bf16_t)val;
      atomicMax(&fmu[o], __float_as_uint((float)bv16));
      fB [b*16384 + o*1024 + role*128 + hl] = bv16;            // m-major (raw)
      fBT[b*16384 + (role*128 + hl)*16 + o] = bv16;            // q-major
      csacc += (float)bv16;
    }
    if (half == 0) phs[hwl*18 + 17] = csacc;
    __syncthreads();
    if (half == 1) {
      float cs = phs[hwl*18 + 17] + csacc;
      csum[b*1024 + hw] = cs;
      atomicMax(cmu, __float_as_uint(cs));
    }
    if (t < 16) fmaxp[b*128 + role*16 + t] = __uint_as_float(fmu[t]);
    __syncthreads();
    if (t == 0) cmaxp[b*8 + role] = __uint_as_float(cmu[0]);
    // xsum partial for this (b, role): L2-hot re-read, thread owns channel c = t
    {
      const f32x4* xr = (const f32x4*)(xb + t*1024 + role*128);
      float s4 = 0.f;
      #pragma unroll
      for (int j = 0; j < 32; ++j) { f32x4 v = xr[j]; s4 += v[0] + v[1] + v[2] + v[3]; }
      xsump[(b*8 + role)*256 + t] = s4;
    }
    return;
  }
  if (bid < 464) {                       // ---- E1 = emb @ gc1_w ----
    int n = bid - 444;
    float* er = (float*)sp;
    for (int i = t; i < 300; i += 256) er[i] = emb[n*300 + i];
    __syncthreads();
    float acc = 0.f;
    for (int d = 0; d < 300; ++d) acc += er[d] * gc1_w[d*256 + t];
    E1[n*256 + t] = acc;
    return;
  }
  if (bid < 765) {                       // ---- WG1 rows / bg1 ----
    int d0 = bid - 464;                  // 0..300
    float* er = (float*)sp;
    if (d0 < 300) { for (int i = t; i < 300; i += 256) er[i] = wo[d0*300 + i]; }
    else          { for (int i = t; i < 300; i += 256) er[i] = bo[i]; }
    __syncthreads();
    float acc = 0.f;
    for (int e = 0; e < 300; ++e) acc += er[e] * gc1_w[e*256 + t];
    if (d0 < 300) WG1[d0*256 + t] = acc; else bg1[t] = acc;
    return;
  }
  {                                      // ---- k_xt: raw-reshape transpose ----
    int id = bid - 765;                  // 0..1023
    int bb = id >> 6, tile = id & 63;
    int q0 = (tile >> 2) * 64, c0 = (tile & 3) * 64;
    bf16_t* tl = (bf16_t*)sp;            // [64][74]
    const float* xbb = x + bb*262144;
    #pragma unroll
    for (int k = 0; k < 16; ++k) {
      int idx = k*256 + t, qi = idx >> 6, ci = idx & 63;
      tl[ci*74 + qi] = (bf16_t)xbb[(q0 + qi)*256 + c0 + ci];
    }
    __syncthreads();
    #pragma unroll
    for (int k = 0; k < 16; ++k) {
      int idx = k*256 + t, ci = idx >> 6, qi = idx & 63;
      xT[bb*262144 + (c0 + ci)*1024 + q0 + qi] = tl[ci*74 + qi];
    }
    return;
  }
}

// =================== LAUNCH B: k_mid1 (18 blocks x 512) ===================
__global__ __launch_bounds__(512) void k_mid1(
    const float* adj, const float* qkv, const float* E1,
    const float* glob_w, const float* xsump, const float* s_raw,
    const float* fmaxp, const float* cmaxp,
    float* n1g, float* adjng, float* rsAg, float* AE1g,
    float* dgd, float* mcol, float* fmaxb, float* cmaxb) {
  __shared__ __align__(16) float sp[12480];
  int t = threadIdx.x;
  if (blockIdx.x == 0) {                 // ---- attention -> n1 ----
    float* A  = sp;            // 6000 q
    float* Bs = A + 6000;      // 6000 k
    float* att  = Bs + 6000;   // 400
    float* wsum = att + 400;   // 20
    for (int i = t; i < 6000; i += 512) { A[i] = qkv[i]; Bs[i] = qkv[6000 + i]; }
    __syncthreads();
    if (t < 400) {
      int i = t / 20, j = t % 20;
      float acc = 0.f;
      for (int d = 0; d < 300; ++d) acc += A[i*300 + d] * Bs[j*300 + d];
      att[t] = acc * 0.05773502691896258f;  // 1/sqrt(300)
    }
    __syncthreads();
    if (t < 20) {
      float m = -1e30f;
      for (int j = 0; j < 20; ++j) m = fmaxf(m, att[t*20 + j]);
      float s = 0.f;
      for (int j = 0; j < 20; ++j) { float e = __expf(att[t*20 + j] - m); att[t*20 + j] = e; s += e; }
      float inv = 1.f / s;
      for (int j = 0; j < 20; ++j) att[t*20 + j] *= inv;
    }
    __syncthreads();
    if (t < 20) {
      float s = 0.f;
      for (int i = 0; i < 20; ++i) s += att[i*20 + t];
      wsum[t] = s * 0.05f;
    }
    __syncthreads();
    if (t < 300) {
      const float* v = qkv + 12000;
      float acc = 0.f;
      for (int j = 0; j < 20; ++j) acc += wsum[j] * v[j*300 + t];
      n1g[t] = acc;
    }
    return;
  }
  if (blockIdx.x == 1) {                 // ---- adjn / rsA / AE1 ----
    float* drt = sp;           // 20
    float* an  = sp + 32;      // 400
    if (t < 20) {
      float s = 1.f;
      for (int j = 0; j < 20; ++j) s += adj[t*20 + j];
      drt[t] = rsqrtf(s);
    }
    __syncthreads();
    if (t < 400) {
      int i = t / 20, j = t % 20;
      float a = adj[t] + (i == j ? 1.f : 0.f);
      float v = drt[i] * a * drt[j];
      an[t] = v;
      adjng[t] = v;
    }
    __syncthreads();
    if (t < 20) {
      float s = 0.f;
      for (int m = 0; m < 20; ++m) s += an[t*20 + m];
      rsAg[t] = s;
    }
    if (t < 256) {
      float e[20];
      #pragma unroll
      for (int m = 0; m < 20; ++m) e[m] = E1[m*256 + t];
      for (int n = 0; n < 20; ++n) {
        float acc = 0.f;
        #pragma unroll
        for (int m = 0; m < 20; ++m) acc += an[n*20 + m] * e[m];
        AE1g[n*256 + t] = acc;
      }
    }
    return;
  }
  // ---- dgm + fmax/cmax reduce, b = blockIdx.x-2 ----
  int b = blockIdx.x - 2;
  float* xm = sp;            // 256
  float* redm = xm + 256;    // 8
  float* reds = redm + 8;    // 8
  float* gpart = reds + 8;   // 256: glob_w partials [m=t>>4][pp=t&15]
  if (t < 256) {
    float s = 0.f;
    #pragma unroll
    for (int r = 0; r < 8; ++r) s += xsump[(b*8 + r)*256 + t];
    xm[t] = s * (1.f / 1024.f);
  }
  if (t >= 256 && t < 272) {
    int m = t - 256; float fm = 0.f;
    for (int r = 0; r < 8; ++r) fm = fmaxf(fm, fmaxp[b*128 + r*16 + m]);
    fmaxb[b*16 + m] = fm;
  }
  if (t == 272) {
    float cm = 0.f;
    for (int r = 0; r < 8; ++r) cm = fmaxf(cm, cmaxp[b*8 + r]);
    cmaxb[b] = cm;
  }
  __syncthreads();
  if (t < 256) {   // parallel glob_w partials: m = t>>4 (0..15), pp = t&15
    float gp = 0.f;
    #pragma unroll
    for (int k = 0; k < 16; ++k)
      gp += glob_w[(t >> 4)*256 + (t & 15)*16 + k] * xm[(t & 15)*16 + k];
    gpart[t] = gp;
  }
  float v0 = s_raw[b*1024 + t], v1 = s_raw[b*1024 + 512 + t];
  float m = fmaxf(v0, v1);
  #pragma unroll
  for (int off = 32; off; off >>= 1) m = fmaxf(m, __shfl_xor(m, off, 64));
  int wv = t >> 6, ll = t & 63;
  if (ll == 0) redm[wv] = m;
  __syncthreads();
  if (t < 16) {    // reduce gpart -> dgd
    float g = 0.f;
    #pragma unroll
    for (int pp = 0; pp < 16; ++pp) g += gpart[t*16 + pp];
    dgd[b*16 + t] = 0.5f * tanhf(0.5f * g);   // sigmoid(g) - 0.5
  }
  float bm = redm[0];
  #pragma unroll
  for (int i = 1; i < 8; ++i) bm = fmaxf(bm, redm[i]);
  float e0 = __expf(v0 - bm), e1 = __expf(v1 - bm);
  float s2 = e0 + e1;
  #pragma unroll
  for (int off = 32; off; off >>= 1) s2 += __shfl_xor(s2, off, 64);
  if (ll == 0) reds[wv] = s2;
  __syncthreads();
  float tot = 0.f;
  #pragma unroll
  for (int i = 0; i < 8; ++i) tot += reds[i];
  float inv = 1.f / tot;
  mcol[b*1024 + t]       = e0 * inv;
  mcol[b*1024 + 512 + t] = e1 * inv;
}

// =================== LAUNCH C: k_w1 (38 blocks) ===================
// w1part[i][c] = sum_{d in [8i, 8i+8) ∩ [0,300)} n1[d] * WG1[d][c]
__global__ __launch_bounds__(256) void k_w1(const float* n1g, const float* WG1,
                                            float* w1part) {
  int t = threadIdx.x, i = blockIdx.x, d0 = i*8;
  float acc = 0.f;
  #pragma unroll
  for (int k = 0; k < 8; ++k) {
    int d = d0 + k;
    if (d < 300) acc += n1g[d] * WG1[d*256 + t];
  }
  w1part[i*256 + t] = acc;
}

// =================== LAUNCH D: k_gu (32 blocks, 8-col slices) ===================
__global__ __launch_bounds__(256) void k_gu(const float* w1part,
    const float* bg1, const float* AE1g, const float* rsAg, const float* adjng,
    const float* gc2_w, const float* final_w, float* upart) {
  __shared__ float adjns[400], rsAs[32], w1s[256], h2s[176], rgs[8];
  __shared__ float g1s[20*260];   // rows padded to 260
  __shared__ float gs2[2048];     // [256 d][8 cl]
  int t = threadIdx.x, c0 = blockIdx.x * 8;
  for (int i = t; i < 400; i += 256) adjns[i] = adjng[i];
  if (t < 20) rsAs[t] = rsAg[t];
  #pragma unroll
  for (int k2 = 0; k2 < 8; ++k2) {       // stage gc2 slice (independent loads)
    int idx = k2*256 + t, d = idx >> 3, cl = idx & 7;
    gs2[idx] = gc2_w[d*256 + c0 + cl];
  }
  {                                      // w1 = bg1 + sum of partials
    float acc = bg1[t];
    #pragma unroll
    for (int i = 0; i < 38; ++i) acc += w1part[i*256 + t];
    w1s[t] = acc;
  }
  float ae[20];
  #pragma unroll
  for (int k2 = 0; k2 < 20; ++k2) ae[k2] = AE1g[k2*256 + t];
  __syncthreads();
  #pragma unroll
  for (int k2 = 0; k2 < 20; ++k2)
    g1s[k2*260 + t] = fmaxf(ae[k2] + rsAs[k2] * w1s[t], 0.f);
  __syncthreads();
  int cl = t & 7, n = t >> 3;            // n 0..32, use n<20
  if (n < 20) {
    float acc = 0.f;
    for (int d = 0; d < 256; ++d) acc += g1s[n*260 + d] * gs2[d*8 + cl];
    h2s[n*8 + cl] = acc;
  }
  __syncthreads();
  if (t < 8) {
    float rga = 0.f;
    for (int nn = 0; nn < 20; ++nn) {
      float a2 = 0.f;
      #pragma unroll
      for (int m = 0; m < 20; ++m) a2 += adjns[nn*20 + m] * h2s[m*8 + t];
      rga += fmaxf(a2, 0.f);
    }
    rgs[t] = rga;
  }
  __syncthreads();
  {                                      // upart over this block's 8-k slice
    float acc = 0.f;
    const float* fw = final_w + t*512 + 256 + c0;
    #pragma unroll
    for (int kk = 0; kk < 8; ++kk) acc += fw[kk] * rgs[kk];
    upart[blockIdx.x*256 + t] = acc;
  }
}

// =================== LAUNCH E: k_main (round-6 schedule + T4 lean barriers) ===================
// S[p,q] = sum_m e'[p,m] f[m,q] (MFMA) + 0.5*a[p]*c[q]; E=exp(S-Mb); rowsum;
// S2u += E @ x_r; T = x_r - S2u/rs; out = relu(M@T^T + mcol*u + x).
// p-tile 32, grid (32,16) = 512 blocks (2/CU), XCD remap (2 batches/XCD).
// 2 st per barrier (16 barriers); bv/a0 prefetched one super-iter ahead.
// In-loop barriers drain lgkmcnt ONLY -> prefetched global loads stay in flight.
__global__ __launch_bounds__(256) void k_main(const float* x, const bf16_t* fB,
    const bf16_t* fBT, const bf16_t* xT, const bf16_t* M16, const float* fmaxb,
    const float* mcol, const float* upart, const float* dgd, const float* csum,
    const float* cmaxb, float* out) {
  int flat = blockIdx.y * 32 + blockIdx.x;
  int b  = (flat & 7) * 2 + ((flat >> 3) >> 5);   // bijective XCD remap
  int p0 = ((flat >> 3) & 31) * 32;
  int t = threadIdx.x, w = t >> 6, l = t & 63, lr = l & 15, quad = l >> 4;
  int qh = w >> 1, ph = w & 1;
  __shared__ __align__(16) char smem[16896];       // union: {PT dbuf(2x2 tiles) | e_s} / T_ls
  bf16_t* PT0  = (bf16_t*)smem;                    // 2 buf x 2 tiles x [32][40]
  bf16_t* e_s  = (bf16_t*)(smem + 10240);          // [32][40] (m>=16 zero)
  bf16_t* T_ls = (bf16_t*)smem;                    // [32][264] phase 2
  __shared__ float Mb_s[32], fmax_s[16], u_s[256], rsinv_s[32], dgd_s[16];
  __shared__ float c_s[1024], ha_s[32], rs_s[2][32];
  const float*  xb   = x   + b*262144;
  const bf16_t* fBb  = fB  + b*16384;
  const bf16_t* fBTb = fBT + b*16384;
  const bf16_t* xTb  = xT  + b*262144;
  for (int i = t; i < 1280; i += 256) e_s[i] = (bf16_t)0.f;
  {
    float us = 0.f;
    #pragma unroll
    for (int j = 0; j < 32; ++j) us += upart[j*256 + t];
    u_s[t] = us;
  }
  for (int i = t; i < 1024; i += 256) c_s[i] = csum[b*1024 + i];
  if (t < 16) { fmax_s[t] = fmaxb[b*16 + t]; dgd_s[t] = dgd[b*16 + t]; }
  __syncthreads();
  for (int i = t; i < 512; i += 256) {       // e'[p,m] = x_phi * (sig(g[m])-0.5)
    int p = i >> 4, m = i & 15;
    e_s[p*40 + m] = (bf16_t)((float)fBb[p0*16 + i] * dgd_s[m]);
  }
  __syncthreads();
  if (t < 32) {
    float a = 0.f;
    #pragma unroll
    for (int m = 0; m < 16; ++m) a += (float)fBb[(p0 + t)*16 + m];
    float ha = 0.5f * a;
    ha_s[t] = ha;
    float mb = ha * cmaxb[b];
    #pragma unroll
    for (int m = 0; m < 16; ++m) mb += fmaxf((float)e_s[t*40 + m], 0.f) * fmax_s[m];
    Mb_s[t] = mb;  // exact upper bound on row max of S
  }
  __syncthreads();
  bf16x8 be = *(const bf16x8*)(e_s + (ph*16 + lr)*40 + quad*8);
  float mb_lane = Mb_s[ph*16 + lr];
  float ha_lane = ha_s[ph*16 + lr];
  float rs = 0.f;
  f32x4 acc[2][4];  // S2u[p = pf*16+quad*4+r][c = w*64+cf*16+lr]
  #pragma unroll
  for (int i = 0; i < 2; ++i)
    #pragma unroll
    for (int j = 0; j < 4; ++j) acc[i][j] = (f32x4){0.f, 0.f, 0.f, 0.f};
  bf16x8 zer;
  #pragma unroll
  for (int j = 0; j < 8; ++j) zer[j] = (bf16_t)0.f;
  bf16x8 a0[2], a0n[2];
  a0[0] = a0[1] = a0n[0] = a0n[1] = zer;
  if (quad < 2) {
    a0[0] = *(const bf16x8*)(fBTb + (qh*16 + lr)*16 + quad*8);
    a0[1] = *(const bf16x8*)(fBTb + (32 + qh*16 + lr)*16 + quad*8);
  }
  const bf16_t* xrow = xTb + (w*64 + lr)*1024 + quad*8;
  bf16x8 bv[2][4], bvn[2][4];
  #pragma unroll
  for (int k = 0; k < 2; ++k)
    #pragma unroll
    for (int cf = 0; cf < 4; ++cf)
      bv[k][cf] = *(const bf16x8*)(xrow + cf*16384 + k*32);
  int cur = 0;
  for (int u2 = 0; u2 < 16; ++u2) {
    f32x4 z = {0.f, 0.f, 0.f, 0.f};
    f32x4 s0 = MFMA(a0[0], be, z);   // D[q=(2u2)*32+qh*16+quad*4+r][p=ph*16+lr]
    f32x4 s1 = MFMA(a0[1], be, z);   // st 2u2+1
    if (u2 < 15) {                   // prefetch next super-iter (stays in flight)
      if (quad < 2) {
        a0n[0] = *(const bf16x8*)(fBTb + ((u2*2 + 2)*32 + qh*16 + lr)*16 + quad*8);
        a0n[1] = *(const bf16x8*)(fBTb + ((u2*2 + 3)*32 + qh*16 + lr)*16 + quad*8);
      }
      #pragma unroll
      for (int k = 0; k < 2; ++k)
        #pragma unroll
        for (int cf = 0; cf < 4; ++cf)
          bvn[k][cf] = *(const bf16x8*)(xrow + cf*16384 + (u2*2 + 2 + k)*32);
    }
    bf16_t* PTc = PT0 + cur*2560;
    bf16x4 pv0, pv1;
    #pragma unroll
    for (int r = 0; r < 4; ++r) {
      float S0 = s0[r] + ha_lane * c_s[(u2*2)*32 + qh*16 + quad*4 + r];
      float E0 = __expf(S0 - mb_lane);
      rs += E0; pv0[r] = (bf16_t)E0;
      float S1 = s1[r] + ha_lane * c_s[(u2*2 + 1)*32 + qh*16 + quad*4 + r];
      float E1v = __expf(S1 - mb_lane);
      rs += E1v; pv1[r] = (bf16_t)E1v;
    }
    *(bf16x4*)(PTc + (ph*16 + lr)*40 + qh*16 + quad*4)        = pv0;
    *(bf16x4*)(PTc + 1280 + (ph*16 + lr)*40 + qh*16 + quad*4) = pv1;
    LEAN_BARRIER();                  // drain LDS writes only; vmcnt stays in flight
    #pragma unroll
    for (int k = 0; k < 2; ++k) {
      bf16x8 ap0 = *(const bf16x8*)(PTc + k*1280 + lr*40 + quad*8);
      bf16x8 ap1 = *(const bf16x8*)(PTc + k*1280 + (16 + lr)*40 + quad*8);
      #pragma unroll
      for (int cf = 0; cf < 4; ++cf) {
        acc[0][cf] = MFMA(ap0, bv[k][cf], acc[0][cf]);
        acc[1][cf] = MFMA(ap1, bv[k][cf], acc[1][cf]);
      }
    }
    if (u2 < 15) {
      #pragma unroll
      for (int k = 0; k < 2; ++k) {
        a0[k] = a0n[k];
        #pragma unroll
        for (int cf = 0; cf < 4; ++cf) bv[k][cf] = bvn[k][cf];
      }
    }
    cur ^= 1;
  }
  rs += __shfl_xor(rs, 16, 64);
  rs += __shfl_xor(rs, 32, 64);          // qh-half rowsum for p = ph*16+lr
  if (l < 16) rs_s[qh][ph*16 + lr] = rs;
  LEAN_BARRIER();   // rs staged (LDS); all PT/e_s reads drained -> T_ls may overwrite
  if (t < 32) rsinv_s[t] = 1.f / fmaxf(rs_s[0][t] + rs_s[1][t], 1e-30f);
  LEAN_BARRIER();
  #pragma unroll
  for (int pf = 0; pf < 2; ++pf)
    #pragma unroll
    for (int cf = 0; cf < 4; ++cf)
      #pragma unroll
      for (int r = 0; r < 4; ++r) {
        int p = pf*16 + quad*4 + r;
        int c = w*64 + cf*16 + lr;
        float tv = xb[(p0 + p)*256 + c] - acc[pf][cf][r] * rsinv_s[p];
        T_ls[p*264 + c] = (bf16_t)tv;    // spiral[p][c]
      }
  LEAN_BARRIER();
  f32x4 acc2[4][2];  // D2[o = w*64+of*16+quad*4+r][p = pf*16+lr]
  #pragma unroll
  for (int i = 0; i < 4; ++i)
    #pragma unroll
    for (int j = 0; j < 2; ++j) acc2[i][j] = (f32x4){0.f, 0.f, 0.f, 0.f};
  for (int c0 = 0; c0 < 256; c0 += 32) {
    bf16x8 am[4], bt[2];
    #pragma unroll
    for (int of = 0; of < 4; ++of)
      am[of] = *(const bf16x8*)(M16 + (w*64 + of*16 + lr)*256 + c0 + quad*8);
    #pragma unroll
    for (int pf = 0; pf < 2; ++pf)
      bt[pf] = *(const bf16x8*)(T_ls + (pf*16 + lr)*264 + c0 + quad*8);
    #pragma unroll
    for (int of = 0; of < 4; ++of)
      #pragma unroll
      for (int pf = 0; pf < 2; ++pf) acc2[of][pf] = MFMA(am[of], bt[pf], acc2[of][pf]);
  }
  float* outb = out + b*262144;
  #pragma unroll
  for (int of = 0; of < 4; ++of)
    #pragma unroll
    for (int pf = 0; pf < 2; ++pf)
      #pragma unroll
      for (int r = 0; r < 4; ++r) {
        int o = w*64 + of*16 + quad*4 + r;
        int pg = p0 + pf*16 + lr;
        float v = acc2[of][pf][r] + mcol[b*1024 + pg] * u_s[o] + xb[o*1024 + pg];
        outb[o*1024 + pg] = fmaxf(v, 0.f);
      }
}

// ---------------- launch ----------------

extern "C" void kernel_launch(void* const* d_in, const int* in_sizes, int n_in,
                              void* d_out, int out_size, void* d_ws, size_t ws_size,
                              hipStream_t stream) {
  (void)in_sizes; (void)n_in; (void)out_size; (void)ws_size;
  const float* x       = (const float*)d_in[0];
  const float* emb     = (const float*)d_in[1];
  const float* adj     = (const float*)d_in[2];
  const float* wq      = (const float*)d_in[3];
  const float* bq      = (const float*)d_in[4];
  const float* wk      = (const float*)d_in[5];
  const float* bk      = (const float*)d_in[6];
  const float* wv      = (const float*)d_in[7];
  const float* bv      = (const float*)d_in[8];
  const float* wo      = (const float*)d_in[9];
  const float* bo      = (const float*)d_in[10];
  const float* phi_w   = (const float*)d_in[11];
  const float* phi_b   = (const float*)d_in[12];
  const float* glob_w  = (const float*)d_in[13];
  const float* gc1_w   = (const float*)d_in[14];
  const float* gc2_w   = (const float*)d_in[15];
  const float* gw_w    = (const float*)d_in[16];
  const float* s2l_w   = (const float*)d_in[17];
  const float* final_w = (const float*)d_in[19];
  float* out = (float*)d_out;

  float* W = (float*)d_ws;
  float* qkv    = W + 0;        // 18000 -> 18048
  float* xsump  = W + 18048;    // 32768 -> 50816
  float* s_raw  = W + 50816;    // 16384 -> 67200
  float* mcol   = W + 67200;    // 16384 -> 83584
  float* fmaxb  = W + 83584;    // 256   -> 83840
  float* dgd    = W + 83840;    // 256   -> 84096
  float* csum   = W + 84096;    // 16384 -> 100480
  float* cmaxb  = W + 100480;   // 64    -> 100544
  float* fmaxp  = W + 100544;   // 2048  -> 102592
  float* cmaxp  = W + 102592;   // 128   -> 102720
  float* E1     = W + 102720;   // 5120  -> 107840
  float* WG1    = W + 107840;   // 76800 -> 184640
  float* bg1    = W + 184640;   // 256   -> 184896
  float* n1     = W + 184896;   // 320   -> 185216
  float* adjn   = W + 185216;   // 448   -> 185664
  float* rsA    = W + 185664;   // 64    -> 185728
  float* AE1    = W + 185728;   // 5120  -> 190848
  float* upart  = W + 190848;   // 8192  -> 199040
  float* w1part = W + 199040;   // 9728  -> 208768 floats (835072 B)
  bf16_t* M16 = (bf16_t*)((char*)d_ws + 851968);   // 128 KB
  bf16_t* fB  = (bf16_t*)((char*)d_ws + 983040);   // 512 KB (m-major raw)
  bf16_t* fBT = (bf16_t*)((char*)d_ws + 1507328);  // 512 KB (q-major)
  bf16_t* xT  = (bf16_t*)((char*)d_ws + 2031616);  // 8 MB  (x transposed bf16)
  // total ws usage ~9.95 MB

  k_front<<<1789, 256, 0, stream>>>(final_w, gw_w, emb, wq, bq, wk, bk, wv, bv, x,
                                    phi_w, phi_b, s2l_w, gc1_w, wo, bo,
                                    M16, qkv, fB, fBT, s_raw, xsump, csum,
                                    fmaxp, cmaxp, xT, E1, WG1, bg1);
  k_mid1<<<18, 512, 0, stream>>>(adj, qkv, E1, glob_w, xsump, s_raw,
                                 fmaxp, cmaxp,
                                 n1, adjn, rsA, AE1, dgd, mcol, fmaxb, cmaxb);
  k_w1<<<38, 256, 0, stream>>>(n1, WG1, w1part);
  k_gu<<<32, 256, 0, stream>>>(w1part, bg1, AE1, rsA, adjn, gc2_w, final_w, upart);
  k_main<<<dim3(32, 16), 256, 0, stream>>>(x, fB, fBT, xT, M16, fmaxb, mcol, upart,
                                           dgd, csum, cmaxb, out);
}

// Round 12
// 199.279 us; speedup vs baseline: 1.1958x; 1.0003x over previous
//
#include <hip/hip_runtime.h>
#include <hip/hip_bf16.h>

// Inputs/outputs are FLOAT32 (reference dtype). bf16 used only internally for MFMA.
typedef __bf16 bf16_t;
typedef bf16_t bf16x8 __attribute__((ext_vector_type(8)));
typedef bf16_t bf16x4 __attribute__((ext_vector_type(4)));
typedef float  f32x4  __attribute__((ext_vector_type(4)));

#define MFMA(a,b,c) __builtin_amdgcn_mfma_f32_16x16x32_bf16((a),(b),(c),0,0,0)
// T4 lean barrier: drain LDS only; global prefetches stay in flight across it.
#define LEAN_BARRIER() asm volatile("s_waitcnt lgkmcnt(0)\n\ts_barrier" ::: "memory")

// =================== LAUNCH A: k_front (1789 blocks) ===================
// roles by blockIdx.x:
//   [0,256)     : M = final_w[:, :256] @ gw_w  (bf16)
//   [256,316)   : qkv = emb @ {wq,wk,wv} + bias
//   [316,444)   : phis (8 roles x 16 b): fB, fBT, s_raw, csum, fmax/cmax, xsump
//   [444,464)   : E1 = emb @ gc1_w  [20][256]
//   [464,765)   : WG1 = wo @ gc1_w [300][256]; row 300 = bg1 = bo @ gc1_w
//   [765,1789)  : xT transpose: raw [1024q][256c] fp32 -> xT [256c][1024q] bf16
__global__ __launch_bounds__(256) void k_front(
    const float* final_w, const float* gw_w, const float* emb,
    const float* wq, const float* bq, const float* wk, const float* bk,
    const float* wv, const float* bvv, const float* x,
    const float* phi_w, const float* phi_b, const float* s2l_w,
    const float* gc1_w, const float* wo, const float* bo,
    bf16_t* M16, float* qkv, bf16_t* fB, bf16_t* fBT, float* s_raw,
    float* xsump, float* csum, float* fmaxp, float* cmaxp, bf16_t* xT,
    float* E1, float* WG1, float* bg1) {
  __shared__ __align__(16) char sp[27648];
  int bid = blockIdx.x, t = threadIdx.x;
  if (bid < 256) {                       // ---- k_M ----
    float* fw = (float*)sp;
    int o = bid, c = t;
    fw[c] = final_w[o*512 + c];
    __syncthreads();
    float acc = 0.f;
    for (int k = 0; k < 256; ++k) acc += fw[k] * gw_w[k*256 + c];
    M16[o*256 + c] = (bf16_t)acc;
    return;
  }
  if (bid < 316) {                       // ---- k_qkv ----
    int id = bid - 256;
    int mat = id / 20, row = id % 20;
    const float* W  = mat == 0 ? wq : (mat == 1 ? wk : wv);
    const float* Bb = mat == 0 ? bq : (mat == 1 ? bk : bvv);
    float* er = (float*)sp;
    for (int i = t; i < 300; i += 256) er[i] = emb[row*300 + i];
    __syncthreads();
    for (int o = t; o < 300; o += 256) {
      float acc = Bb[o];
      for (int d = 0; d < 300; ++d) acc += er[d] * W[d*300 + o];
      qkv[(mat*20 + row)*300 + o] = acc;
    }
    return;
  }
  if (bid < 444) {                       // ---- k_phis ----
    int id = bid - 316;
    int b = id >> 3, role = id & 7;
    const float* xb = x + b*262144;
    float* pw = (float*)sp;              // 4096
    float* wi = pw + 4096;               // 256
    float* pb = wi + 256;                // 16
    float* phs = pb + 16;                // [128][18]
    unsigned* fmu = (unsigned*)(phs + 2304);  // 16
    unsigned* cmu = fmu + 16;            // 1
    for (int i = t; i < 4096; i += 256) pw[i] = phi_w[i];
    wi[t] = s2l_w[t];
    if (t < 16) { pb[t] = phi_b[t]; fmu[t] = 0u; }
    if (t == 0) cmu[0] = 0u;
    __syncthreads();
    int hwl = t & 127, half = t >> 7;
    int hw = role*128 + hwl;
    float ph[16];
    #pragma unroll
    for (int o = 0; o < 16; ++o) ph[o] = 0.f;
    float sacc = 0.f;
    for (int ci = 0; ci < 128; ++ci) {
      int c = half*128 + ci;
      float xv = xb[c*1024 + hw];
      sacc += wi[c] * xv;
      #pragma unroll
      for (int o = 0; o < 16; ++o) ph[o] += pw[o*256 + c] * xv;
    }
    if (half == 0) {
      #pragma unroll
      for (int o = 0; o < 16; ++o) phs[hwl*18 + o] = ph[o];
      phs[hwl*18 + 16] = sacc;
    }
    __syncthreads();
    if (half == 1) {
      #pragma unroll
      for (int o = 0; o < 16; ++o) phs[hwl*18 + o] += ph[o];
      s_raw[b*1024 + hw] = phs[hwl*18 + 16] + sacc;
    }
    __syncthreads();
    float csacc = 0.f;
    #pragma unroll
    for (int i = 0; i < 8; ++i) {
      int j = i*256 + t;
      int o = j >> 7, hl = j & 127;
      float val = fmaxf(phs[hl*18 + o] + pb[o], 0.f);
      bf16_t bv16 = (bf16_t)val;
      atomicMax(&fmu[o], __float_as_uint((float)bv16));
      fB [b*16384 + o*1024 + role*128 + hl] = bv16;            // m-major (raw)
      fBT[b*16384 + (role*128 + hl)*16 + o] = bv16;            // q-major
      csacc += (float)bv16;
    }
    if (half == 0) phs[hwl*18 + 17] = csacc;
    __syncthreads();
    if (half == 1) {
      float cs = phs[hwl*18 + 17] + csacc;
      csum[b*1024 + hw] = cs;
      atomicMax(cmu, __float_as_uint(cs));
    }
    if (t < 16) fmaxp[b*128 + role*16 + t] = __uint_as_float(fmu[t]);
    __syncthreads();
    if (t == 0) cmaxp[b*8 + role] = __uint_as_float(cmu[0]);
    // xsum partial for this (b, role): L2-hot re-read, thread owns channel c = t
    {
      const f32x4* xr = (const f32x4*)(xb + t*1024 + role*128);
      float s4 = 0.f;
      #pragma unroll
      for (int j = 0; j < 32; ++j) { f32x4 v = xr[j]; s4 += v[0] + v[1] + v[2] + v[3]; }
      xsump[(b*8 + role)*256 + t] = s4;
    }
    return;
  }
  if (bid < 464) {                       // ---- E1 = emb @ gc1_w ----
    int n = bid - 444;
    float* er = (float*)sp;
    for (int i = t; i < 300; i += 256) er[i] = emb[n*300 + i];
    __syncthreads();
    float acc = 0.f;
    for (int d = 0; d < 300; ++d) acc += er[d] * gc1_w[d*256 + t];
    E1[n*256 + t] = acc;
    return;
  }
  if (bid < 765) {                       // ---- WG1 rows / bg1 ----
    int d0 = bid - 464;                  // 0..300
    float* er = (float*)sp;
    if (d0 < 300) { for (int i = t; i < 300; i += 256) er[i] = wo[d0*300 + i]; }
    else          { for (int i = t; i < 300; i += 256) er[i] = bo[i]; }
    __syncthreads();
    float acc = 0.f;
    for (int e = 0; e < 300; ++e) acc += er[e] * gc1_w[e*256 + t];
    if (d0 < 300) WG1[d0*256 + t] = acc; else bg1[t] = acc;
    return;
  }
  {                                      // ---- k_xt: raw-reshape transpose ----
    int id = bid - 765;                  // 0..1023
    int bb = id >> 6, tile = id & 63;
    int q0 = (tile >> 2) * 64, c0 = (tile & 3) * 64;
    bf16_t* tl = (bf16_t*)sp;            // [64][74]
    const float* xbb = x + bb*262144;
    #pragma unroll
    for (int k = 0; k < 16; ++k) {
      int idx = k*256 + t, qi = idx >> 6, ci = idx & 63;
      tl[ci*74 + qi] = (bf16_t)xbb[(q0 + qi)*256 + c0 + ci];
    }
    __syncthreads();
    #pragma unroll
    for (int k = 0; k < 16; ++k) {
      int idx = k*256 + t, ci = idx >> 6, qi = idx & 63;
      xT[bb*262144 + (c0 + ci)*1024 + q0 + qi] = tl[ci*74 + qi];
    }
    return;
  }
}

// =================== LAUNCH B: k_mid1 (18 blocks x 512) ===================
__global__ __launch_bounds__(512) void k_mid1(
    const float* adj, const float* qkv, const float* E1,
    const float* glob_w, const float* xsump, const float* s_raw,
    const float* fmaxp, const float* cmaxp,
    float* n1g, float* adjng, float* rsAg, float* AE1g,
    float* dgd, float* mcol, float* fmaxb, float* cmaxb) {
  __shared__ __align__(16) float sp[12480];
  int t = threadIdx.x;
  if (blockIdx.x == 0) {                 // ---- attention -> n1 ----
    float* A  = sp;            // 6000 q
    float* Bs = A + 6000;      // 6000 k
    float* att  = Bs + 6000;   // 400
    float* wsum = att + 400;   // 20
    for (int i = t; i < 6000; i += 512) { A[i] = qkv[i]; Bs[i] = qkv[6000 + i]; }
    __syncthreads();
    if (t < 400) {
      int i = t / 20, j = t % 20;
      float acc = 0.f;
      for (int d = 0; d < 300; ++d) acc += A[i*300 + d] * Bs[j*300 + d];
      att[t] = acc * 0.05773502691896258f;  // 1/sqrt(300)
    }
    __syncthreads();
    if (t < 20) {
      float m = -1e30f;
      for (int j = 0; j < 20; ++j) m = fmaxf(m, att[t*20 + j]);
      float s = 0.f;
      for (int j = 0; j < 20; ++j) { float e = __expf(att[t*20 + j] - m); att[t*20 + j] = e; s += e; }
      float inv = 1.f / s;
      for (int j = 0; j < 20; ++j) att[t*20 + j] *= inv;
    }
    __syncthreads();
    if (t < 20) {
      float s = 0.f;
      for (int i = 0; i < 20; ++i) s += att[i*20 + t];
      wsum[t] = s * 0.05f;
    }
    __syncthreads();
    if (t < 300) {
      const float* v = qkv + 12000;
      float acc = 0.f;
      for (int j = 0; j < 20; ++j) acc += wsum[j] * v[j*300 + t];
      n1g[t] = acc;
    }
    return;
  }
  if (blockIdx.x == 1) {                 // ---- adjn / rsA / AE1 ----
    float* drt = sp;           // 20
    float* an  = sp + 32;      // 400
    if (t < 20) {
      float s = 1.f;
      for (int j = 0; j < 20; ++j) s += adj[t*20 + j];
      drt[t] = rsqrtf(s);
    }
    __syncthreads();
    if (t < 400) {
      int i = t / 20, j = t % 20;
      float a = adj[t] + (i == j ? 1.f : 0.f);
      float v = drt[i] * a * drt[j];
      an[t] = v;
      adjng[t] = v;
    }
    __syncthreads();
    if (t < 20) {
      float s = 0.f;
      for (int m = 0; m < 20; ++m) s += an[t*20 + m];
      rsAg[t] = s;
    }
    if (t < 256) {
      float e[20];
      #pragma unroll
      for (int m = 0; m < 20; ++m) e[m] = E1[m*256 + t];
      for (int n = 0; n < 20; ++n) {
        float acc = 0.f;
        #pragma unroll
        for (int m = 0; m < 20; ++m) acc += an[n*20 + m] * e[m];
        AE1g[n*256 + t] = acc;
      }
    }
    return;
  }
  // ---- dgm + fmax/cmax reduce, b = blockIdx.x-2 ----
  int b = blockIdx.x - 2;
  float* xm = sp;            // 256
  float* redm = xm + 256;    // 8
  float* reds = redm + 8;    // 8
  float* gpart = reds + 8;   // 256: glob_w partials [m=t>>4][pp=t&15]
  if (t < 256) {
    float s = 0.f;
    #pragma unroll
    for (int r = 0; r < 8; ++r) s += xsump[(b*8 + r)*256 + t];
    xm[t] = s * (1.f / 1024.f);
  }
  if (t >= 256 && t < 272) {
    int m = t - 256; float fm = 0.f;
    for (int r = 0; r < 8; ++r) fm = fmaxf(fm, fmaxp[b*128 + r*16 + m]);
    fmaxb[b*16 + m] = fm;
  }
  if (t == 272) {
    float cm = 0.f;
    for (int r = 0; r < 8; ++r) cm = fmaxf(cm, cmaxp[b*8 + r]);
    cmaxb[b] = cm;
  }
  __syncthreads();
  if (t < 256) {   // parallel glob_w partials: m = t>>4 (0..15), pp = t&15
    float gp = 0.f;
    #pragma unroll
    for (int k = 0; k < 16; ++k)
      gp += glob_w[(t >> 4)*256 + (t & 15)*16 + k] * xm[(t & 15)*16 + k];
    gpart[t] = gp;
  }
  float v0 = s_raw[b*1024 + t], v1 = s_raw[b*1024 + 512 + t];
  float m = fmaxf(v0, v1);
  #pragma unroll
  for (int off = 32; off; off >>= 1) m = fmaxf(m, __shfl_xor(m, off, 64));
  int wv = t >> 6, ll = t & 63;
  if (ll == 0) redm[wv] = m;
  __syncthreads();
  if (t < 16) {    // reduce gpart -> dgd
    float g = 0.f;
    #pragma unroll
    for (int pp = 0; pp < 16; ++pp) g += gpart[t*16 + pp];
    dgd[b*16 + t] = 0.5f * tanhf(0.5f * g);   // sigmoid(g) - 0.5
  }
  float bm = redm[0];
  #pragma unroll
  for (int i = 1; i < 8; ++i) bm = fmaxf(bm, redm[i]);
  float e0 = __expf(v0 - bm), e1 = __expf(v1 - bm);
  float s2 = e0 + e1;
  #pragma unroll
  for (int off = 32; off; off >>= 1) s2 += __shfl_xor(s2, off, 64);
  if (ll == 0) reds[wv] = s2;
  __syncthreads();
  float tot = 0.f;
  #pragma unroll
  for (int i = 0; i < 8; ++i) tot += reds[i];
  float inv = 1.f / tot;
  mcol[b*1024 + t]       = e0 * inv;
  mcol[b*1024 + 512 + t] = e1 * inv;
}

// =================== LAUNCH C: k_w1 (38 blocks) ===================
// w1part[i][c] = sum_{d in [8i, 8i+8) ∩ [0,300)} n1[d] * WG1[d][c]
__global__ __launch_bounds__(256) void k_w1(const float* n1g, const float* WG1,
                                            float* w1part) {
  int t = threadIdx.x, i = blockIdx.x, d0 = i*8;
  float acc = 0.f;
  #pragma unroll
  for (int k = 0; k < 8; ++k) {
    int d = d0 + k;
    if (d < 300) acc += n1g[d] * WG1[d*256 + t];
  }
  w1part[i*256 + t] = acc;
}

// =================== LAUNCH D: k_gu (32 blocks, 8-col slices) ===================
__global__ __launch_bounds__(256) void k_gu(const float* w1part,
    const float* bg1, const float* AE1g, const float* rsAg, const float* adjng,
    const float* gc2_w, const float* final_w, float* upart) {
  __shared__ float adjns[400], rsAs[32], w1s[256], h2s[176], rgs[8];
  __shared__ float g1s[20*260];   // rows padded to 260
  __shared__ float gs2[2048];     // [256 d][8 cl]
  int t = threadIdx.x, c0 = blockIdx.x * 8;
  for (int i = t; i < 400; i += 256) adjns[i] = adjng[i];
  if (t < 20) rsAs[t] = rsAg[t];
  #pragma unroll
  for (int k2 = 0; k2 < 8; ++k2) {       // stage gc2 slice (independent loads)
    int idx = k2*256 + t, d = idx >> 3, cl = idx & 7;
    gs2[idx] = gc2_w[d*256 + c0 + cl];
  }
  {                                      // w1 = bg1 + sum of partials
    float acc = bg1[t];
    #pragma unroll
    for (int i = 0; i < 38; ++i) acc += w1part[i*256 + t];
    w1s[t] = acc;
  }
  float ae[20];
  #pragma unroll
  for (int k2 = 0; k2 < 20; ++k2) ae[k2] = AE1g[k2*256 + t];
  __syncthreads();
  #pragma unroll
  for (int k2 = 0; k2 < 20; ++k2)
    g1s[k2*260 + t] = fmaxf(ae[k2] + rsAs[k2] * w1s[t], 0.f);
  __syncthreads();
  int cl = t & 7, n = t >> 3;            // n 0..32, use n<20
  if (n < 20) {
    float acc = 0.f;
    for (int d = 0; d < 256; ++d) acc += g1s[n*260 + d] * gs2[d*8 + cl];
    h2s[n*8 + cl] = acc;
  }
  __syncthreads();
  if (t < 8) {
    float rga = 0.f;
    for (int nn = 0; nn < 20; ++nn) {
      float a2 = 0.f;
      #pragma unroll
      for (int m = 0; m < 20; ++m) a2 += adjns[nn*20 + m] * h2s[m*8 + t];
      rga += fmaxf(a2, 0.f);
    }
    rgs[t] = rga;
  }
  __syncthreads();
  {                                      // upart over this block's 8-k slice
    float acc = 0.f;
    const float* fw = final_w + t*512 + 256 + c0;
    #pragma unroll
    for (int kk = 0; kk < 8; ++kk) acc += fw[kk] * rgs[kk];
    upart[blockIdx.x*256 + t] = acc;
  }
}

// =================== LAUNCH E: k_main (explicit ping-pong dbuf) ===================
// Round-6 schedule, u2-loop unrolled x2 with statically-named register sets
// (A = even u2, B = odd u2) so the compiler cannot sink the prefetch loads:
// each half reloads its OWN set right after its PV MFMAs (last read), giving a
// true one-half-iteration + 2-barrier prefetch window. Lean barriers throughout.
__global__ __launch_bounds__(256) void k_main(const float* x, const bf16_t* fB,
    const bf16_t* fBT, const bf16_t* xT, const bf16_t* M16, const float* fmaxb,
    const float* mcol, const float* upart, const float* dgd, const float* csum,
    const float* cmaxb, float* out) {
  int flat = blockIdx.y * 32 + blockIdx.x;
  int b  = (flat & 7) * 2 + ((flat >> 3) >> 5);   // bijective XCD remap
  int p0 = ((flat >> 3) & 31) * 32;
  int t = threadIdx.x, w = t >> 6, l = t & 63, lr = l & 15, quad = l >> 4;
  int qh = w >> 1, ph = w & 1;
  __shared__ __align__(16) char smem[16896];       // union: {PT dbuf(2x2 tiles) | e_s} / T_ls
  bf16_t* PT0  = (bf16_t*)smem;                    // buf0 tiles @0,1280; buf1 @2560,3840
  bf16_t* e_s  = (bf16_t*)(smem + 10240);          // [32][40] (m>=16 zero)
  bf16_t* T_ls = (bf16_t*)smem;                    // [32][264] phase 2
  __shared__ float Mb_s[32], fmax_s[16], u_s[256], rsinv_s[32], dgd_s[16];
  __shared__ float c_s[1024], ha_s[32], rs_s[2][32];
  const float*  xb   = x   + b*262144;
  const bf16_t* fBb  = fB  + b*16384;
  const bf16_t* fBTb = fBT + b*16384;
  const bf16_t* xTb  = xT  + b*262144;
  for (int i = t; i < 1280; i += 256) e_s[i] = (bf16_t)0.f;
  {
    float us = 0.f;
    #pragma unroll
    for (int j = 0; j < 32; ++j) us += upart[j*256 + t];
    u_s[t] = us;
  }
  for (int i = t; i < 1024; i += 256) c_s[i] = csum[b*1024 + i];
  if (t < 16) { fmax_s[t] = fmaxb[b*16 + t]; dgd_s[t] = dgd[b*16 + t]; }
  __syncthreads();
  for (int i = t; i < 512; i += 256) {       // e'[p,m] = x_phi * (sig(g[m])-0.5)
    int p = i >> 4, m = i & 15;
    e_s[p*40 + m] = (bf16_t)((float)fBb[p0*16 + i] * dgd_s[m]);
  }
  __syncthreads();
  if (t < 32) {
    float a = 0.f;
    #pragma unroll
    for (int m = 0; m < 16; ++m) a += (float)fBb[(p0 + t)*16 + m];
    float ha = 0.5f * a;
    ha_s[t] = ha;
    float mb = ha * cmaxb[b];
    #pragma unroll
    for (int m = 0; m < 16; ++m) mb += fmaxf((float)e_s[t*40 + m], 0.f) * fmax_s[m];
    Mb_s[t] = mb;  // exact upper bound on row max of S
  }
  __syncthreads();
  bf16x8 be = *(const bf16x8*)(e_s + (ph*16 + lr)*40 + quad*8);
  float mb_lane = Mb_s[ph*16 + lr];
  float ha_lane = ha_s[ph*16 + lr];
  float rs = 0.f;
  f32x4 acc[2][4];  // S2u[p = pf*16+quad*4+r][c = w*64+cf*16+lr]
  #pragma unroll
  for (int i = 0; i < 2; ++i)
    #pragma unroll
    for (int j = 0; j < 4; ++j) acc[i][j] = (f32x4){0.f, 0.f, 0.f, 0.f};
  bf16x8 zer;
  #pragma unroll
  for (int j = 0; j < 8; ++j) zer[j] = (bf16_t)0.f;
  const bf16_t* xrow = xTb + (w*64 + lr)*1024 + quad*8;
  // Set A: st {4i, 4i+1}; Set B: st {4i+2, 4i+3}
  bf16x8 a0A[2], a0B[2], bvA[2][4], bvB[2][4];
  a0A[0] = a0A[1] = a0B[0] = a0B[1] = zer;
  if (quad < 2) {
    a0A[0] = *(const bf16x8*)(fBTb + (0*32 + qh*16 + lr)*16 + quad*8);
    a0A[1] = *(const bf16x8*)(fBTb + (1*32 + qh*16 + lr)*16 + quad*8);
    a0B[0] = *(const bf16x8*)(fBTb + (2*32 + qh*16 + lr)*16 + quad*8);
    a0B[1] = *(const bf16x8*)(fBTb + (3*32 + qh*16 + lr)*16 + quad*8);
  }
  #pragma unroll
  for (int k = 0; k < 2; ++k)
    #pragma unroll
    for (int cf = 0; cf < 4; ++cf) {
      bvA[k][cf] = *(const bf16x8*)(xrow + cf*16384 + (0 + k)*32);
      bvB[k][cf] = *(const bf16x8*)(xrow + cf*16384 + (2 + k)*32);
    }
  for (int i = 0; i < 8; ++i) {
    // ---------- H0: u2 = 2i (st 4i, 4i+1), set A, PT buf0 ----------
    {
      f32x4 z = {0.f, 0.f, 0.f, 0.f};
      f32x4 s0 = MFMA(a0A[0], be, z);
      f32x4 s1 = MFMA(a0A[1], be, z);
      bf16x4 pv0, pv1;
      #pragma unroll
      for (int r = 0; r < 4; ++r) {
        float S0 = s0[r] + ha_lane * c_s[(4*i)*32 + qh*16 + quad*4 + r];
        float E0 = __expf(S0 - mb_lane);
        rs += E0; pv0[r] = (bf16_t)E0;
        float S1 = s1[r] + ha_lane * c_s[(4*i + 1)*32 + qh*16 + quad*4 + r];
        float E1v = __expf(S1 - mb_lane);
        rs += E1v; pv1[r] = (bf16_t)E1v;
      }
      *(bf16x4*)(PT0 + (ph*16 + lr)*40 + qh*16 + quad*4)        = pv0;
      *(bf16x4*)(PT0 + 1280 + (ph*16 + lr)*40 + qh*16 + quad*4) = pv1;
      LEAN_BARRIER();
      #pragma unroll
      for (int k = 0; k < 2; ++k) {
        bf16x8 ap0 = *(const bf16x8*)(PT0 + k*1280 + lr*40 + quad*8);
        bf16x8 ap1 = *(const bf16x8*)(PT0 + k*1280 + (16 + lr)*40 + quad*8);
        #pragma unroll
        for (int cf = 0; cf < 4; ++cf) {
          acc[0][cf] = MFMA(ap0, bvA[k][cf], acc[0][cf]);
          acc[1][cf] = MFMA(ap1, bvA[k][cf], acc[1][cf]);
        }
      }
      if (i < 7) {   // reload set A for st {4i+4, 4i+5}; used next outer iter H0
        if (quad < 2) {
          a0A[0] = *(const bf16x8*)(fBTb + ((4*i + 4)*32 + qh*16 + lr)*16 + quad*8);
          a0A[1] = *(const bf16x8*)(fBTb + ((4*i + 5)*32 + qh*16 + lr)*16 + quad*8);
        }
        #pragma unroll
        for (int k = 0; k < 2; ++k)
          #pragma unroll
          for (int cf = 0; cf < 4; ++cf)
            bvA[k][cf] = *(const bf16x8*)(xrow + cf*16384 + (4*i + 4 + k)*32);
      }
    }
    // ---------- H1: u2 = 2i+1 (st 4i+2, 4i+3), set B, PT buf1 ----------
    {
      f32x4 z = {0.f, 0.f, 0.f, 0.f};
      f32x4 s0 = MFMA(a0B[0], be, z);
      f32x4 s1 = MFMA(a0B[1], be, z);
      bf16x4 pv0, pv1;
      #pragma unroll
      for (int r = 0; r < 4; ++r) {
        float S0 = s0[r] + ha_lane * c_s[(4*i + 2)*32 + qh*16 + quad*4 + r];
        float E0 = __expf(S0 - mb_lane);
        rs += E0; pv0[r] = (bf16_t)E0;
        float S1 = s1[r] + ha_lane * c_s[(4*i + 3)*32 + qh*16 + quad*4 + r];
        float E1v = __expf(S1 - mb_lane);
        rs += E1v; pv1[r] = (bf16_t)E1v;
      }
      *(bf16x4*)(PT0 + 2560 + (ph*16 + lr)*40 + qh*16 + quad*4) = pv0;
      *(bf16x4*)(PT0 + 3840 + (ph*16 + lr)*40 + qh*16 + quad*4) = pv1;
      LEAN_BARRIER();
      #pragma unroll
      for (int k = 0; k < 2; ++k) {
        bf16x8 ap0 = *(const bf16x8*)(PT0 + 2560 + k*1280 + lr*40 + quad*8);
        bf16x8 ap1 = *(const bf16x8*)(PT0 + 2560 + k*1280 + (16 + lr)*40 + quad*8);
        #pragma unroll
        for (int cf = 0; cf < 4; ++cf) {
          acc[0][cf] = MFMA(ap0, bvB[k][cf], acc[0][cf]);
          acc[1][cf] = MFMA(ap1, bvB[k][cf], acc[1][cf]);
        }
      }
      if (i < 7) {   // reload set B for st {4i+6, 4i+7}; used next outer iter H1
        if (quad < 2) {
          a0B[0] = *(const bf16x8*)(fBTb + ((4*i + 6)*32 + qh*16 + lr)*16 + quad*8);
          a0B[1] = *(const bf16x8*)(fBTb + ((4*i + 7)*32 + qh*16 + lr)*16 + quad*8);
        }
        #pragma unroll
        for (int k = 0; k < 2; ++k)
          #pragma unroll
          for (int cf = 0; cf < 4; ++cf)
            bvB[k][cf] = *(const bf16x8*)(xrow + cf*16384 + (4*i + 6 + k)*32);
      }
    }
  }
  rs += __shfl_xor(rs, 16, 64);
  rs += __shfl_xor(rs, 32, 64);          // qh-half rowsum for p = ph*16+lr
  if (l < 16) rs_s[qh][ph*16 + lr] = rs;
  LEAN_BARRIER();   // rs staged (LDS); all PT/e_s reads drained -> T_ls may overwrite
  if (t < 32) rsinv_s[t] = 1.f / fmaxf(rs_s[0][t] + rs_s[1][t], 1e-30f);
  LEAN_BARRIER();
  #pragma unroll
  for (int pf = 0; pf < 2; ++pf)
    #pragma unroll
    for (int cf = 0; cf < 4; ++cf)
      #pragma unroll
      for (int r = 0; r < 4; ++r) {
        int p = pf*16 + quad*4 + r;
        int c = w*64 + cf*16 + lr;
        float tv = xb[(p0 + p)*256 + c] - acc[pf][cf][r] * rsinv_s[p];
        T_ls[p*264 + c] = (bf16_t)tv;    // spiral[p][c]
      }
  LEAN_BARRIER();
  f32x4 acc2[4][2];  // D2[o = w*64+of*16+quad*4+r][p = pf*16+lr]
  #pragma unroll
  for (int i = 0; i < 4; ++i)
    #pragma unroll
    for (int j = 0; j < 2; ++j) acc2[i][j] = (f32x4){0.f, 0.f, 0.f, 0.f};
  for (int c0 = 0; c0 < 256; c0 += 32) {
    bf16x8 am[4], bt[2];
    #pragma unroll
    for (int of = 0; of < 4; ++of)
      am[of] = *(const bf16x8*)(M16 + (w*64 + of*16 + lr)*256 + c0 + quad*8);
    #pragma unroll
    for (int pf = 0; pf < 2; ++pf)
      bt[pf] = *(const bf16x8*)(T_ls + (pf*16 + lr)*264 + c0 + quad*8);
    #pragma unroll
    for (int of = 0; of < 4; ++of)
      #pragma unroll
      for (int pf = 0; pf < 2; ++pf) acc2[of][pf] = MFMA(am[of], bt[pf], acc2[of][pf]);
  }
  float* outb = out + b*262144;
  #pragma unroll
  for (int of = 0; of < 4; ++of)
    #pragma unroll
    for (int pf = 0; pf < 2; ++pf)
      #pragma unroll
      for (int r = 0; r < 4; ++r) {
        int o = w*64 + of*16 + quad*4 + r;
        int pg = p0 + pf*16 + lr;
        float v = acc2[of][pf][r] + mcol[b*1024 + pg] * u_s[o] + xb[o*1024 + pg];
        outb[o*1024 + pg] = fmaxf(v, 0.f);
      }
}

// ---------------- launch ----------------

extern "C" void kernel_launch(void* const* d_in, const int* in_sizes, int n_in,
                              void* d_out, int out_size, void* d_ws, size_t ws_size,
                              hipStream_t stream) {
  (void)in_sizes; (void)n_in; (void)out_size; (void)ws_size;
  const float* x       = (const float*)d_in[0];
  const float* emb     = (const float*)d_in[1];
  const float* adj     = (const float*)d_in[2];
  const float* wq      = (const float*)d_in[3];
  const float* bq      = (const float*)d_in[4];
  const float* wk      = (const float*)d_in[5];
  const float* bk      = (const float*)d_in[6];
  const float* wv      = (const float*)d_in[7];
  const float* bv      = (const float*)d_in[8];
  const float* wo      = (const float*)d_in[9];
  const float* bo      = (const float*)d_in[10];
  const float* phi_w   = (const float*)d_in[11];
  const float* phi_b   = (const float*)d_in[12];
  const float* glob_w  = (const float*)d_in[13];
  const float* gc1_w   = (const float*)d_in[14];
  const float* gc2_w   = (const float*)d_in[15];
  const float* gw_w    = (const float*)d_in[16];
  const float* s2l_w   = (const float*)d_in[17];
  const float* final_w = (const float*)d_in[19];
  float* out = (float*)d_out;

  float* W = (float*)d_ws;
  float* qkv    = W + 0;        // 18000 -> 18048
  float* xsump  = W + 18048;    // 32768 -> 50816
  float* s_raw  = W + 50816;    // 16384 -> 67200
  float* mcol   = W + 67200;    // 16384 -> 83584
  float* fmaxb  = W + 83584;    // 256   -> 83840
  float* dgd    = W + 83840;    // 256   -> 84096
  float* csum   = W + 84096;    // 16384 -> 100480
  float* cmaxb  = W + 100480;   // 64    -> 100544
  float* fmaxp  = W + 100544;   // 2048  -> 102592
  float* cmaxp  = W + 102592;   // 128   -> 102720
  float* E1     = W + 102720;   // 5120  -> 107840
  float* WG1    = W + 107840;   // 76800 -> 184640
  float* bg1    = W + 184640;   // 256   -> 184896
  float* n1     = W + 184896;   // 320   -> 185216
  float* adjn   = W + 185216;   // 448   -> 185664
  float* rsA    = W + 185664;   // 64    -> 185728
  float* AE1    = W + 185728;   // 5120  -> 190848
  float* upart  = W + 190848;   // 8192  -> 199040
  float* w1part = W + 199040;   // 9728  -> 208768 floats (835072 B)
  bf16_t* M16 = (bf16_t*)((char*)d_ws + 851968);   // 128 KB
  bf16_t* fB  = (bf16_t*)((char*)d_ws + 983040);   // 512 KB (m-major raw)
  bf16_t* fBT = (bf16_t*)((char*)d_ws + 1507328);  // 512 KB (q-major)
  bf16_t* xT  = (bf16_t*)((char*)d_ws + 2031616);  // 8 MB  (x transposed bf16)
  // total ws usage ~9.95 MB

  k_front<<<1789, 256, 0, stream>>>(final_w, gw_w, emb, wq, bq, wk, bk, wv, bv, x,
                                    phi_w, phi_b, s2l_w, gc1_w, wo, bo,
                                    M16, qkv, fB, fBT, s_raw, xsump, csum,
                                    fmaxp, cmaxp, xT, E1, WG1, bg1);
  k_mid1<<<18, 512, 0, stream>>>(adj, qkv, E1, glob_w, xsump, s_raw,
                                 fmaxp, cmaxp,
                                 n1, adjn, rsA, AE1, dgd, mcol, fmaxb, cmaxb);
  k_w1<<<38, 256, 0, stream>>>(n1, WG1, w1part);
  k_gu<<<32, 256, 0, stream>>>(w1part, bg1, AE1, rsA, adjn, gc2_w, final_w, upart);
  k_main<<<dim3(32, 16), 256, 0, stream>>>(x, fB, fBT, xT, M16, fmaxb, mcol, upart,
                                           dgd, csum, cmaxb, out);
}